// Round 10
// baseline (3909.047 us; speedup 1.0000x reference)
//
#include <hip/hip_runtime.h>
#include <hip/hip_fp16.h>

#define NN 160
#define KP 81                // kept kz planes (Hermitian half)
#define N3 4096000           // 160^3
#define NLINES 25600         // 160^2 z-lines
#define XWZ 16               // tile width (kz columns) for x/y sweeps
#define NBX 6                // ceil(81/16)
#define XS 12960             // x-stride in complex layout (160*81)
#define TPI 6.28318530717958647692f
#define LAM_F 0.05f
#define SC160 (1.f/160.f)
#define YCOLS 83             // padded LDS row stride in ymid (conflict-free)

// ---------------- complex helpers ----------------
__device__ __forceinline__ float2 cxmul(float2 a, float2 b){
    return make_float2(a.x*b.x - a.y*b.y, a.x*b.y + a.y*b.x);
}
__device__ __forceinline__ float2 cadd(float2 a, float2 b){ return make_float2(a.x+b.x, a.y+b.y); }
__device__ __forceinline__ float2 csub(float2 a, float2 b){ return make_float2(a.x-b.x, a.y-b.y); }
__device__ __forceinline__ float2 cscale(float2 a, float s){ return make_float2(a.x*s, a.y*s); }
__device__ __forceinline__ float2 shfl2(float2 v, int m){
    return make_float2(__shfl_xor(v.x, m, 64), __shfl_xor(v.y, m, 64));
}
__device__ __forceinline__ int br5(int l){
    return ((l&1)<<4)|((l&2)<<2)|(l&4)|((l&8)>>2)|((l&16)>>4);
}
__device__ __forceinline__ float2 h2f(__half2 h){ return __half22float2(h); }
__device__ __forceinline__ __half2 f2h(float2 f){ return __float22half2_rn(f); }
__device__ __forceinline__ __half2 h2zero(){ return f2h(make_float2(0.f,0.f)); }
// rev in revolutions (angle/2pi). v_sin_f32/v_cos_f32 are revolution-input
// on gfx950 -> 1 instr each, no range reduction needed.
__device__ __forceinline__ float fsin_rev(float rev){ return __builtin_amdgcn_sinf(rev); }
__device__ __forceinline__ float fcos_rev(float rev){ return __builtin_amdgcn_cosf(rev); }
template<int SGN>
__device__ __forceinline__ float2 twid(float rev){
    float s = fsin_rev(rev), c = fcos_rev(rev);
    return make_float2(c, (SGN>0) ? -s : s);
}

// ---------------- radix-5 DFT ----------------
template<int SGN>
__device__ __forceinline__ void dft5(float2 y[5]){
    const float C1 = 0.30901699437494742f;
    const float C2 = -0.80901699437494742f;
    const float S1 = 0.95105651629515357f;
    const float S2 = 0.58778525229247312f;
    float2 x0=y[0], x1=y[1], x2=y[2], x3=y[3], x4=y[4];
    float2 t1=cadd(x1,x4), t2=cadd(x2,x3), t3=csub(x1,x4), t4=csub(x2,x3);
    y[0] = cadd(x0, cadd(t1,t2));
    float2 a1 = make_float2(x0.x + C1*t1.x + C2*t2.x, x0.y + C1*t1.y + C2*t2.y);
    float2 a2 = make_float2(x0.x + C2*t1.x + C1*t2.x, x0.y + C2*t1.y + C1*t2.y);
    const float sg = (SGN>0) ? 1.f : -1.f;
    float2 b1 = make_float2(sg*(S1*t3.x + S2*t4.x), sg*(S1*t3.y + S2*t4.y));
    float2 b2 = make_float2(sg*(S2*t3.x - S1*t4.x), sg*(S2*t3.y - S1*t4.y));
    y[1] = make_float2(a1.x + b1.y, a1.y - b1.x);
    y[4] = make_float2(a1.x - b1.y, a1.y + b1.x);
    y[2] = make_float2(a2.x + b2.y, a2.y - b2.x);
    y[3] = make_float2(a2.x - b2.y, a2.y + b2.x);
}

__device__ __forceinline__ float2 bfly(float2 v, int m, float2 tw, int l){
    float2 o = shfl2(v, m);
    float2 s = cadd(v, o);
    float2 d = cxmul(csub(o, v), tw);
    return (l & m) ? d : s;
}

// 160-pt FFT: lane l in [0,32) holds y[n1]=x[n1*32+l] on entry.
// On exit, slot k holds X[k + 5*br5(l)].
template<int SGN>
__device__ __forceinline__ void linefft(float2 y[5], int l){
    dft5<SGN>(y);
    float2 w1 = twid<SGN>((float)l * (1.f/160.f));
    float2 w2 = cxmul(w1,w1);
    float2 w3 = cxmul(w2,w1);
    float2 w4 = cxmul(w2,w2);
    y[1]=cxmul(y[1],w1); y[2]=cxmul(y[2],w2); y[3]=cxmul(y[3],w3); y[4]=cxmul(y[4],w4);
    float2 tw16 = twid<SGN>((float)(l & 15) * (1.f/32.f));
    float2 tw8  = twid<SGN>((float)(l & 7)  * (1.f/16.f));
    float2 tw4  = twid<SGN>((float)(l & 3)  * (1.f/8.f));
    float2 tw2  = twid<SGN>((float)(l & 1)  * (1.f/4.f));
    #pragma unroll
    for (int k=0;k<5;k++){
        float2 v = y[k];
        v = bfly(v,16,tw16,l);
        v = bfly(v, 8,tw8 ,l);
        v = bfly(v, 4,tw4 ,l);
        v = bfly(v, 2,tw2 ,l);
        float2 o = shfl2(v,1);
        v = (l&1) ? csub(o,v) : cadd(v,o);
        y[k] = v;
    }
}

// DIT butterfly: low lane: v + tw*o ; high lane: o - tw*v
__device__ __forceinline__ float2 bflyi(float2 v, int m, float2 tw, int l){
    float2 o = shfl2(v, m);
    float2 t = cxmul(tw, (l & m) ? v : o);
    return (l & m) ? csub(o, t) : cadd(v, t);
}

// inverse 160-pt FFT consuming the forward's permuted register layout:
// entry: slot k lane l = X[k + 5*br5(l)]; exit: y[n1] = x[n1*32+l] (UNscaled).
__device__ __forceinline__ void ilinefft_perm(float2 y[5], int l){
    float2 tw2  = twid<-1>((float)(l & 1)  * (1.f/4.f));
    float2 tw4  = twid<-1>((float)(l & 3)  * (1.f/8.f));
    float2 tw8  = twid<-1>((float)(l & 7)  * (1.f/16.f));
    float2 tw16 = twid<-1>((float)(l & 15) * (1.f/32.f));
    #pragma unroll
    for (int k=0;k<5;k++){
        float2 v = y[k];
        { float2 o = shfl2(v,1); v = (l&1) ? csub(o,v) : cadd(v,o); }
        v = bflyi(v, 2, tw2 , l);
        v = bflyi(v, 4, tw4 , l);
        v = bflyi(v, 8, tw8 , l);
        v = bflyi(v,16, tw16, l);
        y[k] = v;
    }
    float2 w1 = twid<-1>((float)l * (1.f/160.f));
    float2 w2 = cxmul(w1,w1);
    float2 w3 = cxmul(w2,w1);
    float2 w4 = cxmul(w2,w2);
    y[1]=cxmul(y[1],w1); y[2]=cxmul(y[2],w2); y[3]=cxmul(y[3],w3); y[4]=cxmul(y[4],w4);
    dft5<-1>(y);
}

struct RPc {
    __half2* C[3];
    const __half2* M[3];   // pair-interleaved m^2*w: [pair*160 + z] = (even, odd)
};

// analytic kernel ingredients: Q sums over (dy,dz) ball slices, per column
struct QCol {
    float Q1_0, Q1_1;
    float Q2_0, Q2_1, Q2_2;
    float Q3_0, Q3_1, Q3_2, Q3_3;
    float fz2;
};

__device__ __forceinline__ QCol make_qcol(float ay0,float ay1,float ay2,float ay3, int kz){
    float fz = (float)kz * (1.f/160.f);
    float cz1 = fcos_rev(fz);
    float cz2 = 2.f*cz1*cz1 - 1.f;
    float cz3 = 2.f*cz1*cz2 - cz1;
    float az0=1.f, az1=2.f*cz1, az2=2.f*cz2, az3=2.f*cz3;
    float P00=ay0*az0, P01=ay0*az1, P02=ay0*az2, P03=ay0*az3;
    float P10=ay1*az0, P11=ay1*az1, P12=ay1*az2;
    float P20=ay2*az0, P21=ay2*az1, P22=ay2*az2;
    float P30=ay3*az0;
    QCol q;
    q.Q1_0 = P00 + P01 + P10;
    q.Q1_1 = P00;
    q.Q2_0 = P00+P01+P02+P10+P11+P20;
    q.Q2_1 = P00+P01+P10+P11;
    q.Q2_2 = P00;
    q.Q3_0 = P00+P01+P02+P03+P10+P11+P12+P20+P21+P22+P30;
    q.Q3_1 = P00+P01+P02+P10+P11+P12+P20+P21+P22;
    q.Q3_2 = P00+P01+P02+P10+P11+P12+P20+P21;
    q.Q3_3 = P00;
    q.fz2 = fz*fz;
    return q;
}

// all three K_r with one cosine chain. kx in [0,160).
__device__ __forceinline__ void kval3(const QCol& q, float fy2, int kx, float K[3]){
    float c1 = fcos_rev((float)kx * (1.f/160.f));
    float c2 = 2.f*c1*c1 - 1.f;
    float c3 = 2.f*c1*c2 - c1;
    float s1 = (q.Q1_0 + 2.f*c1*q.Q1_1) * (1.f/7.f);
    float s2 = (q.Q2_0 + 2.f*(c1*q.Q2_1 + c2*q.Q2_2)) * (1.f/33.f);
    float s3 = (q.Q3_0 + 2.f*(c1*q.Q3_1 + c2*q.Q3_2 + c3*q.Q3_3)) * (1.f/123.f);
    float fxw = (float)((kx < 80) ? kx : 160 - kx) * (1.f/160.f);
    float k2 = fxw*fxw + fy2 + q.fz2;
    float D = (1.f/3.f) - ((k2 == 0.f) ? 0.f : q.fz2 * __builtin_amdgcn_rcpf(k2));
    K[0] = (1.f - s1) * D;
    K[1] = (1.f - s2) * D;
    K[2] = (1.f - s3) * D;
}

// ---------------- CG reduction helper ----------------
__device__ __forceinline__ void block_atomic_add(double v, double* target){
    #pragma unroll
    for (int off=32; off>0; off>>=1) v += __shfl_down(v, off, 64);
    __shared__ double sm[4];
    int wv = threadIdx.x >> 6;
    if ((threadIdx.x & 63) == 0) sm[wv] = v;
    __syncthreads();
    if (threadIdx.x == 0) atomicAdd(target, sm[0]+sm[1]+sm[2]+sm[3]);
}

// ======== z-axis kernels: wave-local, barrier-free ========
// Forward passes carry 1/160 each axis; inverse passes are UNscaled.
// PM=0: fft real zin. PM=1: p = r + beta*p (beta=S[3]), store p, fft p.
template<int PM>
__global__ __launch_bounds__(256) void fft_z_first(const float* __restrict__ zin,
    const float* __restrict__ rrv, float* __restrict__ ppv,
    __half2* __restrict__ out, const double* __restrict__ S)
{
    __shared__ float2 ldsC[8*162];
    int tid = threadIdx.x, l = tid & 31, g = tid >> 5;
    int fl = g*162;
    size_t base160 = (size_t)blockIdx.x * 2560 + (size_t)(2*g)*160;
    size_t baseC   = (size_t)blockIdx.x * 1296 + (size_t)g*162;
    float beta = PM ? (float)S[3] : 0.f;
    float2 y[5];
    #pragma unroll
    for (int n1=0;n1<5;n1++){
        int n = n1*32 + l;
        float a, b;
        if (PM){
            a = rrv[base160 + n]       + beta * ppv[base160 + n];
            b = rrv[base160 + 160 + n] + beta * ppv[base160 + 160 + n];
            ppv[base160 + n] = a;
            ppv[base160 + 160 + n] = b;
        } else {
            a = zin[base160 + n];
            b = zin[base160 + 160 + n];
        }
        y[n1] = make_float2(a * SC160, b * SC160);   // fwd 1/160
    }
    linefft<1>(y, l);
    int o5 = 5*br5(l);
    #pragma unroll
    for (int k=0;k<5;k++) ldsC[fl + o5 + k] = y[k];
    #pragma unroll
    for (int t=0;t<6;t++){
        int j = l + 32*t;
        if (j < 162){
            int k = (j < 81) ? j : j - 81;
            float2 Sk = ldsC[fl + k];
            float2 Sm = ldsC[fl + ((160 - k) % 160)];
            float2 o = (j >= 81)
                ? make_float2(0.5f*(Sk.y + Sm.y), -0.5f*(Sk.x - Sm.x))    // B
                : make_float2(0.5f*(Sk.x + Sm.x),  0.5f*(Sk.y - Sm.y));   // A
            out[baseC + j] = f2h(o);
        }
    }
}

// final inverse-z (unscaled) + epilogue.
// FIN=0: Ap=v, S[1]+=<z,v>. FIN=1: r=b-v -> rr,pp, S[0]+=<r,r>.
template<int FIN>
__global__ __launch_bounds__(256) void fft_z_fin(const __half2* __restrict__ in,
    const float* __restrict__ zsp, float* __restrict__ Ap,
    const float* __restrict__ bb, float* __restrict__ rrv, float* __restrict__ ppv,
    double* __restrict__ S)
{
    __shared__ float2 ldsC[8*162];
    float* ldsF = (float*)ldsC;      // region g: floats [324g, 324g+320)
    int tid = threadIdx.x, l = tid & 31, g = tid >> 5;
    int fl = g*162;
    size_t baseC   = (size_t)blockIdx.x * 1296 + (size_t)g*162;
    size_t base160 = (size_t)blockIdx.x * 2560 + (size_t)(2*g)*160;
    int o5 = 5*br5(l);
    float za[5], zb[5], pa[5], pb[5];
    #pragma unroll
    for (int k=0;k<5;k++){
        za[k] = zsp[base160 + o5 + k];
        zb[k] = zsp[base160 + 160 + o5 + k];
        if (FIN){
            pa[k] = bb[base160 + o5 + k];
            pb[k] = bb[base160 + 160 + o5 + k];
        }
    }
    #pragma unroll
    for (int t=0;t<6;t++){
        int j = l + 32*t;
        if (j < 162) ldsC[fl + j] = h2f(in[baseC + j]);
    }
    float2 y[5];
    #pragma unroll
    for (int n1=0;n1<5;n1++){
        int e = n1*32 + l;
        float2 X;
        if (e <= 80){
            float2 A = ldsC[fl + e], B = ldsC[fl + 81 + e];
            X = make_float2(A.x - B.y, A.y + B.x);
        } else {
            int m = 160 - e;
            float2 A = ldsC[fl + m], B = ldsC[fl + 81 + m];
            X = make_float2(A.x + B.y, B.x - A.y);
        }
        y[n1] = X;
    }
    linefft<-1>(y, l);
    double acc = 0.0;
    int fb = g*324;
    #pragma unroll
    for (int k=0;k<5;k++){
        float va = LAM_F*za[k] + y[k].x;      // inverse unscaled
        float vb = LAM_F*zb[k] + y[k].y;
        if (FIN == 0){
            acc += (double)za[k]*(double)va + (double)zb[k]*(double)vb;
            ldsF[fb + o5 + k] = va;
            ldsF[fb + 160 + o5 + k] = vb;
        } else {
            float ra = pa[k] - va, rb = pb[k] - vb;
            acc += (double)ra*(double)ra + (double)rb*(double)rb;
            ldsF[fb + o5 + k] = ra;
            ldsF[fb + 160 + o5 + k] = rb;
        }
    }
    #pragma unroll
    for (int t=0;t<10;t++){
        int n = l + 32*t;
        float v = ldsF[fb + n];
        if (FIN == 0){
            Ap[base160 + n] = v;
        } else {
            rrv[base160 + n] = v;
            ppv[base160 + n] = v;
        }
    }
    block_atomic_add(acc, FIN ? &S[0] : &S[1]);
}

// ======== fused y-inv / z-mid / y-fwd slab kernel ========
// One block per (ix, r). 512 threads = 16 groups. LDS: plane[160][83] half2
// + per-group spectrum scratch (160 half2) = 63.4 KB.
template<bool PRE>
__global__ __launch_bounds__(512) void fft_ymid(RPc P, const float* __restrict__ mask,
                                                const float* __restrict__ wfull)
{
    __shared__ __half2 plane[160*YCOLS];
    __shared__ __half2 scratch[16*160];
    int r = blockIdx.y;
    int ix = blockIdx.x;
    __half2* C = P.C[r];
    int tid = threadIdx.x, l = tid & 31, g = tid >> 5;   // 16 groups of 32
    size_t gbase = (size_t)ix * XS;
    int o5 = 5*br5(l);

    // early m^2*w loads (pair-interleaved): 5 pairs per group
    __half2 mw[5][5];
    if (PRE){
        const __half2* M = P.M[r];
        #pragma unroll
        for (int j=0;j<5;j++){
            int p = g + 16*j;
            size_t mb = ((size_t)ix*80 + p)*160 + o5;
            #pragma unroll
            for (int k=0;k<5;k++) mw[j][k] = M[mb + k];
        }
    }
    // contiguous slab load
    for (int i = tid; i < 12960; i += 512){
        int row = i / 81, col = i - row*81;
        plane[row*YCOLS + col] = C[gbase + i];
    }
    __syncthreads();
    // inverse y FFT (unscaled) on 81 kz columns
    for (int col = g; col < 81; col += 16){
        float2 y[5];
        #pragma unroll
        for (int n1=0;n1<5;n1++) y[n1] = h2f(plane[(n1*32+l)*YCOLS + col]);
        linefft<-1>(y, l);
        #pragma unroll
        for (int k=0;k<5;k++) plane[(o5+k)*YCOLS + col] = f2h(y[k]);
    }
    __syncthreads();
    // z pass: 5 iy-pairs per group
    __half2* scr = &scratch[g*160];
    #pragma unroll
    for (int j=0;j<5;j++){
        int p = g + 16*j;
        int rA = (2*p)*YCOLS, rB = (2*p+1)*YCOLS;
        float2 y[5];
        #pragma unroll
        for (int n1=0;n1<5;n1++){
            int e = n1*32 + l;
            float2 X;
            if (e <= 80){
                float2 A = h2f(plane[rA + e]), B = h2f(plane[rB + e]);
                X = make_float2(A.x - B.y, A.y + B.x);
            } else {
                int m = 160 - e;
                float2 A = h2f(plane[rA + m]), B = h2f(plane[rB + m]);
                X = make_float2(A.x + B.y, B.x - A.y);
            }
            y[n1] = X;
        }
        linefft<-1>(y, l);
        #pragma unroll
        for (int k=0;k<5;k++){
            float2 m2;
            if (PRE){
                m2 = h2f(mw[j][k]);
            } else {
                size_t i0 = (((size_t)ix*160 + 2*p)*160) + o5 + k;
                float m0 = mask[i0], m1 = mask[i0+160];
                m2 = make_float2(m0*m0*wfull[i0*3+r], m1*m1*wfull[(i0+160)*3+r]);
            }
            scr[o5+k] = f2h(make_float2(y[k].x * m2.x * SC160, y[k].y * m2.y * SC160));
        }
        #pragma unroll
        for (int n1=0;n1<5;n1++) y[n1] = h2f(scr[n1*32+l]);
        linefft<1>(y, l);
        #pragma unroll
        for (int k=0;k<5;k++) scr[o5+k] = f2h(y[k]);
        #pragma unroll
        for (int t=0;t<6;t++){
            int jj = l + 32*t;
            if (jj < 162){
                int k = (jj < 81) ? jj : jj - 81;
                float2 Sk = h2f(scr[k]);
                float2 Sm = h2f(scr[(160-k)%160]);
                float2 o = (jj>=81)
                    ? make_float2(0.5f*(Sk.y+Sm.y), -0.5f*(Sk.x-Sm.x))
                    : make_float2(0.5f*(Sk.x+Sm.x),  0.5f*(Sk.y-Sm.y));
                plane[(jj<81 ? rA : rB) + k] = f2h(o);
            }
        }
    }
    __syncthreads();
    // forward y FFT (scale 1/160)
    for (int col = g; col < 81; col += 16){
        float2 y[5];
        #pragma unroll
        for (int n1=0;n1<5;n1++) y[n1] = h2f(plane[(n1*32+l)*YCOLS + col]);
        linefft<1>(y, l);
        #pragma unroll
        for (int k=0;k<5;k++) plane[(o5+k)*YCOLS + col] = f2h(cscale(y[k], SC160));
    }
    __syncthreads();
    for (int i = tid; i < 12960; i += 512){
        int row = i / 81, col = i - row*81;
        C[gbase + i] = plane[row*YCOLS + col];
    }
}

// ---------------- y-axis sweeps on CF (W=16, 2 cols/group) ----------------
template<int SGN>
__global__ __launch_bounds__(256) void fft_y1(__half2* __restrict__ data)
{
    __shared__ __half2 tile[160*17];
    int b = blockIdx.x;
    int ix = b % 160, zb = (b / 160) * XWZ;
    size_t tbase = (size_t)ix*XS + zb;
    int tid = threadIdx.x, l = tid & 31, q = tid >> 5;
    for (int i = tid; i < 160*XWZ; i += 256){
        int row = i >> 4, zi = i & 15;
        tile[row*17 + zi] = (zb + zi < KP) ? data[tbase + (size_t)row*KP + zi] : h2zero();
    }
    __syncthreads();
    int o5 = 5*br5(l);
    const float SC = (SGN>0) ? SC160 : 1.f;
    #pragma unroll
    for (int cc=0; cc<2; cc++){
        int col = q + 8*cc;
        float2 y[5];
        #pragma unroll
        for (int n1=0;n1<5;n1++) y[n1] = h2f(tile[(l+32*n1)*17 + col]);
        linefft<SGN>(y, l);
        #pragma unroll
        for (int k=0;k<5;k++) tile[(o5+k)*17 + col] = f2h(cscale(y[k], SC));
    }
    __syncthreads();
    for (int i = tid; i < 160*XWZ; i += 256){
        int row = i >> 4, zi = i & 15;
        if (zb + zi < KP) data[tbase + (size_t)row*KP + zi] = tile[row*17 + zi];
    }
}

// ---------------- x-axis kernels with analytic K (W=16, 2 cols/group) ----------------
// spread: C_r = invx( (K_r/160) * fwdx(CF) ); shared fwd FFT, register inverse.
__global__ __launch_bounds__(256) void fft_xK(RPc P, const __half2* __restrict__ in)
{
    __shared__ __half2 tile[160*17];
    int b = blockIdx.x;
    int iy = b % 160, zb = (b / 160) * XWZ;
    size_t tbase = (size_t)iy*KP + zb;
    int tid = threadIdx.x, l = tid & 31, q = tid >> 5;
    for (int i = tid; i < 160*XWZ; i += 256){
        int row = i >> 4, zi = i & 15;
        tile[row*17 + zi] = (zb + zi < KP) ? in[tbase + (size_t)row*XS + zi] : h2zero();
    }
    __syncthreads();
    float fy = (float)((iy < 80) ? iy : iy - 160) * (1.f/160.f);
    float fy2 = fy*fy;
    float cy1 = fcos_rev(fy);
    float cy2 = 2.f*cy1*cy1 - 1.f;
    float cy3 = 2.f*cy1*cy2 - cy1;
    int o5 = 5*br5(l);
    float2 spec[2][5];
    float K3[2][5][3];
    #pragma unroll
    for (int cc=0; cc<2; cc++){
        int col = q + 8*cc;
        QCol qc = make_qcol(1.f, 2.f*cy1, 2.f*cy2, 2.f*cy3, zb + col);
        #pragma unroll
        for (int n1=0;n1<5;n1++) spec[cc][n1] = h2f(tile[(n1*32+l)*17 + col]);
        linefft<1>(spec[cc], l);
        #pragma unroll
        for (int k=0;k<5;k++) kval3(qc, fy2, o5+k, K3[cc][k]);
    }
    #pragma unroll
    for (int r=0; r<3; r++){
        #pragma unroll
        for (int cc=0; cc<2; cc++){
            int col = q + 8*cc;
            float2 acc[5];
            #pragma unroll
            for (int k=0;k<5;k++) acc[k] = cscale(spec[cc][k], K3[cc][k][r] * SC160);
            ilinefft_perm(acc, l);
            #pragma unroll
            for (int n1=0;n1<5;n1++) tile[(n1*32+l)*17 + col] = f2h(acc[n1]);
        }
        __syncthreads();
        __half2* Cr = P.C[r];
        for (int i = tid; i < 160*XWZ; i += 256){
            int row = i >> 4, zi = i & 15;
            if (zb + zi < KP) Cr[tbase + (size_t)row*XS + zi] = tile[row*17 + zi];
        }
        __syncthreads();
    }
}

// gather: CF = invx( sum_r (K_r/160) * fwdx(C_r) ), single tile + reg staging
__global__ __launch_bounds__(256) void fft_xgather(RPc P, __half2* __restrict__ out)
{
    __shared__ __half2 tile[160*17];
    int b = blockIdx.x;
    int iy = b % 160, zb = (b / 160) * XWZ;
    size_t tbase = (size_t)iy*KP + zb;
    int tid = threadIdx.x, l = tid & 31, q = tid >> 5;
    #pragma unroll
    for (int j=0;j<10;j++){
        int i = tid + 256*j;
        int row = i >> 4, zi = i & 15;
        tile[row*17 + zi] = (zb + zi < KP) ? P.C[0][tbase + (size_t)row*XS + zi] : h2zero();
    }
    __syncthreads();
    float fy = (float)((iy < 80) ? iy : iy - 160) * (1.f/160.f);
    float fy2 = fy*fy;
    float cy1 = fcos_rev(fy);
    float cy2 = 2.f*cy1*cy1 - 1.f;
    float cy3 = 2.f*cy1*cy2 - cy1;
    int o5 = 5*br5(l);
    float K3[2][5][3];
    #pragma unroll
    for (int cc=0; cc<2; cc++){
        QCol qc = make_qcol(1.f, 2.f*cy1, 2.f*cy2, 2.f*cy3, zb + q + 8*cc);
        #pragma unroll
        for (int k=0;k<5;k++) kval3(qc, fy2, o5+k, K3[cc][k]);
    }
    // stage C1 early
    __half2 st[10];
    #pragma unroll
    for (int j=0;j<10;j++){
        int i = tid + 256*j;
        int row = i >> 4, zi = i & 15;
        st[j] = (zb + zi < KP) ? P.C[1][tbase + (size_t)row*XS + zi] : h2zero();
    }
    float2 acc[2][5];
    #pragma unroll
    for (int cc=0; cc<2; cc++){
        int col = q + 8*cc;
        float2 y[5];
        #pragma unroll
        for (int n1=0;n1<5;n1++) y[n1] = h2f(tile[(n1*32+l)*17 + col]);
        linefft<1>(y, l);
        #pragma unroll
        for (int k=0;k<5;k++) acc[cc][k] = cscale(y[k], K3[cc][k][0] * SC160);
    }
    __syncthreads();
    #pragma unroll
    for (int j=0;j<10;j++){
        int i = tid + 256*j;
        tile[(i >> 4)*17 + (i & 15)] = st[j];
    }
    __syncthreads();
    // stage C2 early
    #pragma unroll
    for (int j=0;j<10;j++){
        int i = tid + 256*j;
        int row = i >> 4, zi = i & 15;
        st[j] = (zb + zi < KP) ? P.C[2][tbase + (size_t)row*XS + zi] : h2zero();
    }
    #pragma unroll
    for (int cc=0; cc<2; cc++){
        int col = q + 8*cc;
        float2 y[5];
        #pragma unroll
        for (int n1=0;n1<5;n1++) y[n1] = h2f(tile[(n1*32+l)*17 + col]);
        linefft<1>(y, l);
        #pragma unroll
        for (int k=0;k<5;k++) acc[cc][k] = cadd(acc[cc][k], cscale(y[k], K3[cc][k][1] * SC160));
    }
    __syncthreads();
    #pragma unroll
    for (int j=0;j<10;j++){
        int i = tid + 256*j;
        tile[(i >> 4)*17 + (i & 15)] = st[j];
    }
    __syncthreads();
    #pragma unroll
    for (int cc=0; cc<2; cc++){
        int col = q + 8*cc;
        float2 y[5];
        #pragma unroll
        for (int n1=0;n1<5;n1++) y[n1] = h2f(tile[(n1*32+l)*17 + col]);
        linefft<1>(y, l);
        #pragma unroll
        for (int k=0;k<5;k++) acc[cc][k] = cadd(acc[cc][k], cscale(y[k], K3[cc][k][2] * SC160));
        ilinefft_perm(acc[cc], l);
        #pragma unroll
        for (int n1=0;n1<5;n1++) tile[(n1*32+l)*17 + col] = f2h(acc[cc][n1]);
    }
    __syncthreads();
    for (int i = tid; i < 160*XWZ; i += 256){
        int row = i >> 4, zi = i & 15;
        if (zb + zi < KP) out[tbase + (size_t)row*XS + zi] = tile[row*17 + zi];
    }
}

// ---------------- setup / CG vector ops ----------------
// pair-interleaved m^2*w: index i = P*160 + n, lines (2P, 2P+1)
__global__ __launch_bounds__(256) void m2w_kernel(const float* __restrict__ mask,
        const float* __restrict__ w, __half2* __restrict__ M0,
        __half2* __restrict__ M1, __half2* __restrict__ M2)
{
    int i = blockIdx.x*256 + threadIdx.x;
    int Pp = i / 160, n = i - Pp*160;
    size_t i0 = (size_t)(2*Pp)*160 + n;
    size_t i1 = i0 + 160;
    float m0 = mask[i0], m1 = mask[i1];
    float mm0 = m0*m0, mm1 = m1*m1;
    M0[i] = f2h(make_float2(mm0*w[i0*3+0], mm1*w[i1*3+0]));
    M1[i] = f2h(make_float2(mm0*w[i0*3+1], mm1*w[i1*3+1]));
    M2[i] = f2h(make_float2(mm0*w[i0*3+2], mm1*w[i1*3+2]));
}

__global__ __launch_bounds__(256) void copy_kernel(const float* __restrict__ a, float* __restrict__ b){
    int i = blockIdx.x*256 + threadIdx.x;
    b[i] = a[i];
}

#define GSTRIDE (2048*256)
__global__ __launch_bounds__(256) void upd1_kernel(float* __restrict__ x, float* __restrict__ r,
        const float* __restrict__ p, const float* __restrict__ Ap, double* s)
{
    float alpha = (float)(s[0] / (s[1] + 1e-12));
    double acc = 0.0;
    for (int i = blockIdx.x*256 + threadIdx.x; i < N3; i += GSTRIDE){
        x[i] += alpha * p[i];
        float rn = r[i] - alpha * Ap[i];
        r[i] = rn;
        acc += (double)rn * (double)rn;
    }
    block_atomic_add(acc, &s[2]);
}
__global__ void advance_kernel(double* s){
    if (threadIdx.x == 0){
        s[3] = s[2] / (s[0] + 1e-12);   // beta
        s[0] = s[2]; s[1] = 0.0; s[2] = 0.0;
    }
}
__global__ void zero_kernel(double* s){
    if (threadIdx.x < 4) s[threadIdx.x] = 0.0;
}

// ---------------- host orchestration ----------------
extern "C" void kernel_launch(void* const* d_in, const int* in_sizes, int n_in,
                              void* d_out, int out_size, void* d_ws, size_t ws_size,
                              hipStream_t stream)
{
    (void)in_sizes; (void)n_in; (void)out_size;
    const float* w    = (const float*)d_in[0];   // [N3*3], R fastest
    const float* x2   = (const float*)d_in[1];   // [N3]
    const float* mask = (const float*)d_in[2];   // [N3]
    const float* bb   = (const float*)d_in[3];   // [N3]
    float* x = (float*)d_out;
    char* ws = (char*)d_ws;

    size_t off = 0;
    auto alloc = [&](size_t bytes)->void*{
        void* pp = ws + off;
        off += (bytes + 255) & ~(size_t)255;
        return pp;
    };
    const size_t CB = (size_t)NLINES * KP * sizeof(__half2);   // 8.3 MB
    __half2* CF = (__half2*)alloc(CB);
    __half2* C0 = (__half2*)alloc(CB);
    __half2* C1 = (__half2*)alloc(CB);
    __half2* C2 = (__half2*)alloc(CB);
    float*  rr = (float*) alloc((size_t)N3*4);
    float*  pp = (float*) alloc((size_t)N3*4);
    float*  Ap = (float*) alloc((size_t)N3*4);
    double* S  = (double*)alloc(64);
    bool PRE = (ws_size >= off + 3*(((size_t)N3*2 + 255) & ~(size_t)255));
    __half2 *M0=nullptr, *M1=nullptr, *M2=nullptr;
    if (PRE){
        M0 = (__half2*)alloc((size_t)N3*2);
        M1 = (__half2*)alloc((size_t)N3*2);
        M2 = (__half2*)alloc((size_t)N3*2);
    }
    RPc P;
    P.C[0]=C0; P.C[1]=C1; P.C[2]=C2;
    P.M[0]=M0; P.M[1]=M1; P.M[2]=M2;

    zero_kernel<<<1, 64, 0, stream>>>(S);
    if (PRE) m2w_kernel<<<8000, 256, 0, stream>>>(mask, w, M0, M1, M2);
    copy_kernel<<<16000, 256, 0, stream>>>(x2, x);

    const int GX = NBX * 160;    // 960
    // PM: 0 = plain fft of z; 1 = fused p-update. FIN: 1 = initial residual, 0 = CG iter.
    auto applyM = [&](const float* z, int FIN, int PM){
        if (PM) fft_z_first<1><<<1600, 256, 0, stream>>>(z, rr, pp, CF, S);
        else    fft_z_first<0><<<1600, 256, 0, stream>>>(z, rr, pp, CF, S);
        fft_y1<1><<<GX, 256, 0, stream>>>(CF);
        fft_xK<<<GX, 256, 0, stream>>>(P, CF);
        if (PRE) fft_ymid<true ><<<dim3(160,3), 512, 0, stream>>>(P, mask, w);
        else     fft_ymid<false><<<dim3(160,3), 512, 0, stream>>>(P, mask, w);
        fft_xgather<<<GX, 256, 0, stream>>>(P, CF);
        fft_y1<-1><<<GX, 256, 0, stream>>>(CF);
        if (FIN) fft_z_fin<1><<<1600, 256, 0, stream>>>(CF, x, Ap, bb, rr, pp, S);
        else     fft_z_fin<0><<<1600, 256, 0, stream>>>(CF, pp, Ap, bb, rr, pp, S);
    };

    // r = b - M(x2); p = r; rs = <r,r>
    applyM(x, 1, 0);

    for (int it = 0; it < 10; it++){
        applyM(pp, 0, (it == 0) ? 0 : 1);          // Ap = M(p), S[1] = <p,Ap>
        upd1_kernel<<<2048, 256, 0, stream>>>(x, rr, pp, Ap, S);
        if (it < 9) advance_kernel<<<1, 64, 0, stream>>>(S);
    }
}

// Round 11
// 2774.905 us; speedup vs baseline: 1.4087x; 1.4087x over previous
//
#include <hip/hip_runtime.h>
#include <hip/hip_fp16.h>

#define NN 160
#define KP 81                // kept kz planes (Hermitian half)
#define N3 4096000           // 160^3
#define NLINES 25600         // 160^2 z-lines
#define WZ 8                 // tile width for x sweeps
#define NBZ 11               // ceil(81/8)   (x kernels)
#define YW 16                // tile width for y sweeps
#define NBY 6                // ceil(81/16)  (y kernels)
#define XS 12960             // x-stride in complex layout (160*81)
#define TPI 6.28318530717958647692f
#define LAM_F 0.05f
#define SC160 (1.f/160.f)

// ---------------- complex helpers ----------------
__device__ __forceinline__ float2 cxmul(float2 a, float2 b){
    return make_float2(a.x*b.x - a.y*b.y, a.x*b.y + a.y*b.x);
}
__device__ __forceinline__ float2 cadd(float2 a, float2 b){ return make_float2(a.x+b.x, a.y+b.y); }
__device__ __forceinline__ float2 csub(float2 a, float2 b){ return make_float2(a.x-b.x, a.y-b.y); }
__device__ __forceinline__ float2 cscale(float2 a, float s){ return make_float2(a.x*s, a.y*s); }
__device__ __forceinline__ float2 shfl2(float2 v, int m){
    return make_float2(__shfl_xor(v.x, m, 64), __shfl_xor(v.y, m, 64));
}
__device__ __forceinline__ int br5(int l){
    return ((l&1)<<4)|((l&2)<<2)|(l&4)|((l&8)>>2)|((l&16)>>4);
}
__device__ __forceinline__ float2 h2f(__half2 h){ return __half22float2(h); }
__device__ __forceinline__ __half2 f2h(float2 f){ return __float22half2_rn(f); }
__device__ __forceinline__ __half2 h2zero(){ return f2h(make_float2(0.f,0.f)); }
// rev in revolutions (angle/2pi). v_sin_f32/v_cos_f32 are revolution-input
// on gfx950 -> 1 instr each, no range reduction needed.
__device__ __forceinline__ float fsin_rev(float rev){ return __builtin_amdgcn_sinf(rev); }
__device__ __forceinline__ float fcos_rev(float rev){ return __builtin_amdgcn_cosf(rev); }
template<int SGN>
__device__ __forceinline__ float2 twid(float rev){
    float s = fsin_rev(rev), c = fcos_rev(rev);
    return make_float2(c, (SGN>0) ? -s : s);
}

// ---------------- radix-5 DFT ----------------
template<int SGN>
__device__ __forceinline__ void dft5(float2 y[5]){
    const float C1 = 0.30901699437494742f;
    const float C2 = -0.80901699437494742f;
    const float S1 = 0.95105651629515357f;
    const float S2 = 0.58778525229247312f;
    float2 x0=y[0], x1=y[1], x2=y[2], x3=y[3], x4=y[4];
    float2 t1=cadd(x1,x4), t2=cadd(x2,x3), t3=csub(x1,x4), t4=csub(x2,x3);
    y[0] = cadd(x0, cadd(t1,t2));
    float2 a1 = make_float2(x0.x + C1*t1.x + C2*t2.x, x0.y + C1*t1.y + C2*t2.y);
    float2 a2 = make_float2(x0.x + C2*t1.x + C1*t2.x, x0.y + C2*t1.y + C1*t2.y);
    const float sg = (SGN>0) ? 1.f : -1.f;
    float2 b1 = make_float2(sg*(S1*t3.x + S2*t4.x), sg*(S1*t3.y + S2*t4.y));
    float2 b2 = make_float2(sg*(S2*t3.x - S1*t4.x), sg*(S2*t3.y - S1*t4.y));
    y[1] = make_float2(a1.x + b1.y, a1.y - b1.x);
    y[4] = make_float2(a1.x - b1.y, a1.y + b1.x);
    y[2] = make_float2(a2.x + b2.y, a2.y - b2.x);
    y[3] = make_float2(a2.x - b2.y, a2.y + b2.x);
}

__device__ __forceinline__ float2 bfly(float2 v, int m, float2 tw, int l){
    float2 o = shfl2(v, m);
    float2 s = cadd(v, o);
    float2 d = cxmul(csub(o, v), tw);
    return (l & m) ? d : s;
}

// 160-pt FFT: lane l in [0,32) holds y[n1]=x[n1*32+l] on entry.
// On exit, slot k holds X[k + 5*br5(l)].
template<int SGN>
__device__ __forceinline__ void linefft(float2 y[5], int l){
    dft5<SGN>(y);
    float2 w1 = twid<SGN>((float)l * (1.f/160.f));
    float2 w2 = cxmul(w1,w1);
    float2 w3 = cxmul(w2,w1);
    float2 w4 = cxmul(w2,w2);
    y[1]=cxmul(y[1],w1); y[2]=cxmul(y[2],w2); y[3]=cxmul(y[3],w3); y[4]=cxmul(y[4],w4);
    float2 tw16 = twid<SGN>((float)(l & 15) * (1.f/32.f));
    float2 tw8  = twid<SGN>((float)(l & 7)  * (1.f/16.f));
    float2 tw4  = twid<SGN>((float)(l & 3)  * (1.f/8.f));
    float2 tw2  = twid<SGN>((float)(l & 1)  * (1.f/4.f));
    #pragma unroll
    for (int k=0;k<5;k++){
        float2 v = y[k];
        v = bfly(v,16,tw16,l);
        v = bfly(v, 8,tw8 ,l);
        v = bfly(v, 4,tw4 ,l);
        v = bfly(v, 2,tw2 ,l);
        float2 o = shfl2(v,1);
        v = (l&1) ? csub(o,v) : cadd(v,o);
        y[k] = v;
    }
}

// DIT butterfly: low lane: v + tw*o ; high lane: o - tw*v
__device__ __forceinline__ float2 bflyi(float2 v, int m, float2 tw, int l){
    float2 o = shfl2(v, m);
    float2 t = cxmul(tw, (l & m) ? v : o);
    return (l & m) ? csub(o, t) : cadd(v, t);
}

// inverse 160-pt FFT consuming the forward's permuted register layout:
// entry: slot k lane l = X[k + 5*br5(l)]; exit: y[n1] = x[n1*32+l] (UNscaled).
__device__ __forceinline__ void ilinefft_perm(float2 y[5], int l){
    float2 tw2  = twid<-1>((float)(l & 1)  * (1.f/4.f));
    float2 tw4  = twid<-1>((float)(l & 3)  * (1.f/8.f));
    float2 tw8  = twid<-1>((float)(l & 7)  * (1.f/16.f));
    float2 tw16 = twid<-1>((float)(l & 15) * (1.f/32.f));
    #pragma unroll
    for (int k=0;k<5;k++){
        float2 v = y[k];
        { float2 o = shfl2(v,1); v = (l&1) ? csub(o,v) : cadd(v,o); }
        v = bflyi(v, 2, tw2 , l);
        v = bflyi(v, 4, tw4 , l);
        v = bflyi(v, 8, tw8 , l);
        v = bflyi(v,16, tw16, l);
        y[k] = v;
    }
    float2 w1 = twid<-1>((float)l * (1.f/160.f));
    float2 w2 = cxmul(w1,w1);
    float2 w3 = cxmul(w2,w1);
    float2 w4 = cxmul(w2,w2);
    y[1]=cxmul(y[1],w1); y[2]=cxmul(y[2],w2); y[3]=cxmul(y[3],w3); y[4]=cxmul(y[4],w4);
    dft5<-1>(y);
}

struct RPc {
    __half2* C[3];
    const __half* M[3];
};

// analytic kernel ingredients: Q sums over (dy,dz) ball slices, per column
struct QCol {
    float Q1_0, Q1_1;
    float Q2_0, Q2_1, Q2_2;
    float Q3_0, Q3_1, Q3_2, Q3_3;
    float fz2;
};

__device__ __forceinline__ QCol make_qcol(float ay0,float ay1,float ay2,float ay3, int kz){
    float fz = (float)kz * (1.f/160.f);
    float cz1 = fcos_rev(fz);
    float cz2 = 2.f*cz1*cz1 - 1.f;
    float cz3 = 2.f*cz1*cz2 - cz1;
    float az0=1.f, az1=2.f*cz1, az2=2.f*cz2, az3=2.f*cz3;
    float P00=ay0*az0, P01=ay0*az1, P02=ay0*az2, P03=ay0*az3;
    float P10=ay1*az0, P11=ay1*az1, P12=ay1*az2;
    float P20=ay2*az0, P21=ay2*az1, P22=ay2*az2;
    float P30=ay3*az0;
    QCol q;
    q.Q1_0 = P00 + P01 + P10;
    q.Q1_1 = P00;
    q.Q2_0 = P00+P01+P02+P10+P11+P20;
    q.Q2_1 = P00+P01+P10+P11;
    q.Q2_2 = P00;
    q.Q3_0 = P00+P01+P02+P03+P10+P11+P12+P20+P21+P22+P30;
    q.Q3_1 = P00+P01+P02+P10+P11+P12+P20+P21+P22;
    q.Q3_2 = P00+P01+P02+P10+P11+P12+P20+P21;
    q.Q3_3 = P00;
    q.fz2 = fz*fz;
    return q;
}

// all three K_r with one cosine chain. kx in [0,160).
__device__ __forceinline__ void kval3(const QCol& q, float fy2, int kx, float K[3]){
    float c1 = fcos_rev((float)kx * (1.f/160.f));
    float c2 = 2.f*c1*c1 - 1.f;
    float c3 = 2.f*c1*c2 - c1;
    float s1 = (q.Q1_0 + 2.f*c1*q.Q1_1) * (1.f/7.f);
    float s2 = (q.Q2_0 + 2.f*(c1*q.Q2_1 + c2*q.Q2_2)) * (1.f/33.f);
    float s3 = (q.Q3_0 + 2.f*(c1*q.Q3_1 + c2*q.Q3_2 + c3*q.Q3_3)) * (1.f/123.f);
    float fxw = (float)((kx < 80) ? kx : 160 - kx) * (1.f/160.f);
    float k2 = fxw*fxw + fy2 + q.fz2;
    float D = (1.f/3.f) - ((k2 == 0.f) ? 0.f : q.fz2 * __builtin_amdgcn_rcpf(k2));
    K[0] = (1.f - s1) * D;
    K[1] = (1.f - s2) * D;
    K[2] = (1.f - s3) * D;
}

// ---------------- CG reduction helper ----------------
__device__ __forceinline__ void block_atomic_add(double v, double* target){
    #pragma unroll
    for (int off=32; off>0; off>>=1) v += __shfl_down(v, off, 64);
    __shared__ double sm[4];
    int wv = threadIdx.x >> 6;
    if ((threadIdx.x & 63) == 0) sm[wv] = v;
    __syncthreads();
    if (threadIdx.x == 0) atomicAdd(target, sm[0]+sm[1]+sm[2]+sm[3]);
}

// ======== z-axis kernels: wave-local, barrier-free ========
// Forward passes carry 1/160 each axis; inverse passes are UNscaled.
// PM=0: fft real zin. PM=1: p = r + beta*p (beta=S[3]), store p, fft p.
template<int PM>
__global__ __launch_bounds__(256) void fft_z_first(const float* __restrict__ zin,
    const float* __restrict__ rrv, float* __restrict__ ppv,
    __half2* __restrict__ out, const double* __restrict__ S)
{
    __shared__ float2 ldsC[8*162];
    int tid = threadIdx.x, l = tid & 31, g = tid >> 5;
    int fl = g*162;
    size_t base160 = (size_t)blockIdx.x * 2560 + (size_t)(2*g)*160;
    size_t baseC   = (size_t)blockIdx.x * 1296 + (size_t)g*162;
    float beta = PM ? (float)S[3] : 0.f;
    float2 y[5];
    #pragma unroll
    for (int n1=0;n1<5;n1++){
        int n = n1*32 + l;
        float a, b;
        if (PM){
            a = rrv[base160 + n]       + beta * ppv[base160 + n];
            b = rrv[base160 + 160 + n] + beta * ppv[base160 + 160 + n];
            ppv[base160 + n] = a;
            ppv[base160 + 160 + n] = b;
        } else {
            a = zin[base160 + n];
            b = zin[base160 + 160 + n];
        }
        y[n1] = make_float2(a * SC160, b * SC160);   // fwd 1/160
    }
    linefft<1>(y, l);
    int o5 = 5*br5(l);
    #pragma unroll
    for (int k=0;k<5;k++) ldsC[fl + o5 + k] = y[k];
    #pragma unroll
    for (int t=0;t<6;t++){
        int j = l + 32*t;
        if (j < 162){
            int k = (j < 81) ? j : j - 81;
            float2 Sk = ldsC[fl + k];
            float2 Sm = ldsC[fl + ((160 - k) % 160)];
            float2 o = (j >= 81)
                ? make_float2(0.5f*(Sk.y + Sm.y), -0.5f*(Sk.x - Sm.x))    // B
                : make_float2(0.5f*(Sk.x + Sm.x),  0.5f*(Sk.y - Sm.y));   // A
            out[baseC + j] = f2h(o);
        }
    }
}

// fused: inverse-z (unscaled) -> *(m2w_r/160) -> forward-z
template<bool PRE>
__global__ __launch_bounds__(256) void fft_z_mid3(RPc P, const float* __restrict__ mask,
                                                 const float* __restrict__ wfull)
{
    __shared__ float2 ldsC[8*162];
    int r = blockIdx.y;
    __half2* C = P.C[r];
    int tid = threadIdx.x, l = tid & 31, g = tid >> 5;
    int fl = g*162;
    size_t baseC   = (size_t)blockIdx.x * 1296 + (size_t)g*162;
    size_t base160 = (size_t)blockIdx.x * 2560 + (size_t)(2*g)*160;
    int o5 = 5*br5(l);
    float ma[5], mb[5];
    if (PRE){
        const __half* M = P.M[r];
        #pragma unroll
        for (int k=0;k<5;k++){
            ma[k] = __half2float(M[base160 + o5 + k]) * SC160;
            mb[k] = __half2float(M[base160 + 160 + o5 + k]) * SC160;
        }
    } else {
        #pragma unroll
        for (int k=0;k<5;k++){
            size_t ia = base160 + o5 + k, ib = base160 + 160 + o5 + k;
            float m1 = mask[ia], m2 = mask[ib];
            ma[k] = m1*m1*wfull[ia*3 + r] * SC160;
            mb[k] = m2*m2*wfull[ib*3 + r] * SC160;
        }
    }
    #pragma unroll
    for (int t=0;t<6;t++){
        int j = l + 32*t;
        if (j < 162) ldsC[fl + j] = h2f(C[baseC + j]);
    }
    float2 y[5];
    #pragma unroll
    for (int n1=0;n1<5;n1++){
        int e = n1*32 + l;
        float2 X;
        if (e <= 80){
            float2 A = ldsC[fl + e], B = ldsC[fl + 81 + e];
            X = make_float2(A.x - B.y, A.y + B.x);
        } else {
            int m = 160 - e;
            float2 A = ldsC[fl + m], B = ldsC[fl + 81 + m];
            X = make_float2(A.x + B.y, B.x - A.y);
        }
        y[n1] = X;
    }
    linefft<-1>(y, l);
    #pragma unroll
    for (int k=0;k<5;k++){
        float a = y[k].x * ma[k];
        float b = y[k].y * mb[k];
        ldsC[fl + o5 + k] = make_float2(a, b);
    }
    #pragma unroll
    for (int n1=0;n1<5;n1++) y[n1] = ldsC[fl + n1*32 + l];
    linefft<1>(y, l);
    #pragma unroll
    for (int k=0;k<5;k++) ldsC[fl + o5 + k] = y[k];
    #pragma unroll
    for (int t=0;t<6;t++){
        int j = l + 32*t;
        if (j < 162){
            int k = (j < 81) ? j : j - 81;
            float2 Sk = ldsC[fl + k];
            float2 Sm = ldsC[fl + ((160 - k) % 160)];
            float2 o = (j >= 81)
                ? make_float2(0.5f*(Sk.y + Sm.y), -0.5f*(Sk.x - Sm.x))
                : make_float2(0.5f*(Sk.x + Sm.x),  0.5f*(Sk.y - Sm.y));
            C[baseC + j] = f2h(o);
        }
    }
}

// final inverse-z (unscaled) + epilogue.
// FIN=0: Ap=v, S[1]+=<z,v>. FIN=1: r=b-v -> rr,pp, S[0]+=<r,r>.
template<int FIN>
__global__ __launch_bounds__(256) void fft_z_fin(const __half2* __restrict__ in,
    const float* __restrict__ zsp, float* __restrict__ Ap,
    const float* __restrict__ bb, float* __restrict__ rrv, float* __restrict__ ppv,
    double* __restrict__ S)
{
    __shared__ float2 ldsC[8*162];
    float* ldsF = (float*)ldsC;      // region g: floats [324g, 324g+320)
    int tid = threadIdx.x, l = tid & 31, g = tid >> 5;
    int fl = g*162;
    size_t baseC   = (size_t)blockIdx.x * 1296 + (size_t)g*162;
    size_t base160 = (size_t)blockIdx.x * 2560 + (size_t)(2*g)*160;
    int o5 = 5*br5(l);
    float za[5], zb[5], pa[5], pb[5];
    #pragma unroll
    for (int k=0;k<5;k++){
        za[k] = zsp[base160 + o5 + k];
        zb[k] = zsp[base160 + 160 + o5 + k];
        if (FIN){
            pa[k] = bb[base160 + o5 + k];
            pb[k] = bb[base160 + 160 + o5 + k];
        }
    }
    #pragma unroll
    for (int t=0;t<6;t++){
        int j = l + 32*t;
        if (j < 162) ldsC[fl + j] = h2f(in[baseC + j]);
    }
    float2 y[5];
    #pragma unroll
    for (int n1=0;n1<5;n1++){
        int e = n1*32 + l;
        float2 X;
        if (e <= 80){
            float2 A = ldsC[fl + e], B = ldsC[fl + 81 + e];
            X = make_float2(A.x - B.y, A.y + B.x);
        } else {
            int m = 160 - e;
            float2 A = ldsC[fl + m], B = ldsC[fl + 81 + m];
            X = make_float2(A.x + B.y, B.x - A.y);
        }
        y[n1] = X;
    }
    linefft<-1>(y, l);
    double acc = 0.0;
    int fb = g*324;
    #pragma unroll
    for (int k=0;k<5;k++){
        float va = LAM_F*za[k] + y[k].x;      // inverse unscaled
        float vb = LAM_F*zb[k] + y[k].y;
        if (FIN == 0){
            acc += (double)za[k]*(double)va + (double)zb[k]*(double)vb;
            ldsF[fb + o5 + k] = va;
            ldsF[fb + 160 + o5 + k] = vb;
        } else {
            float ra = pa[k] - va, rb = pb[k] - vb;
            acc += (double)ra*(double)ra + (double)rb*(double)rb;
            ldsF[fb + o5 + k] = ra;
            ldsF[fb + 160 + o5 + k] = rb;
        }
    }
    #pragma unroll
    for (int t=0;t<10;t++){
        int n = l + 32*t;
        float v = ldsF[fb + n];
        if (FIN == 0){
            Ap[base160 + n] = v;
        } else {
            rrv[base160 + n] = v;
            ppv[base160 + n] = v;
        }
    }
    block_atomic_add(acc, FIN ? &S[0] : &S[1]);
}

// ---------------- y-axis sweeps (W=16, sequential 2 cols/group) ----------------
// SGN>0 (fwd): scale 1/160 ; SGN<0 (inv): unscaled.
template<int SGN>
__device__ __forceinline__ void ycompute16(float2* tile, int tid){
    int l = tid & 31, q = tid >> 5;
    const float SC = (SGN>0) ? SC160 : 1.f;
    int o5 = 5*br5(l);
    #pragma unroll
    for (int cc=0; cc<2; cc++){
        int col = q + 8*cc;
        float2 y[5];
        #pragma unroll
        for (int n1=0;n1<5;n1++) y[n1] = tile[(l + 32*n1)*17 + col];
        linefft<SGN>(y, l);
        #pragma unroll
        for (int k=0;k<5;k++) tile[(o5+k)*17 + col] = cscale(y[k], SC);
    }
}

// b = zchunk*160 + ix  (zb-outer so line-sharing blocks b, b+160 share an XCD)
template<int SGN>
__global__ __launch_bounds__(256) void fft_y1(__half2* __restrict__ data)
{
    __shared__ float2 tile[160*17];
    int b = blockIdx.x;
    int ix = b % 160, zb = (b / 160) * YW;
    size_t tbase = (size_t)ix*XS + zb;
    int tid = threadIdx.x;
    for (int i = tid; i < 160*YW; i += 256){
        int row = i >> 4, zi = i & 15;
        tile[row*17 + zi] = (zb + zi < KP) ? h2f(data[tbase + (size_t)row*KP + zi]) : make_float2(0.f,0.f);
    }
    __syncthreads();
    ycompute16<SGN>(tile, tid);
    __syncthreads();
    for (int i = tid; i < 160*YW; i += 256){
        int row = i >> 4, zi = i & 15;
        if (zb + zi < KP) data[tbase + (size_t)row*KP + zi] = f2h(tile[row*17 + zi]);
    }
}

template<int SGN>
__global__ __launch_bounds__(256) void fft_y3(RPc P)
{
    __shared__ float2 tile[160*17];
    __half2* data = P.C[blockIdx.y];
    int b = blockIdx.x;
    int ix = b % 160, zb = (b / 160) * YW;
    size_t tbase = (size_t)ix*XS + zb;
    int tid = threadIdx.x;
    for (int i = tid; i < 160*YW; i += 256){
        int row = i >> 4, zi = i & 15;
        tile[row*17 + zi] = (zb + zi < KP) ? h2f(data[tbase + (size_t)row*KP + zi]) : make_float2(0.f,0.f);
    }
    __syncthreads();
    ycompute16<SGN>(tile, tid);
    __syncthreads();
    for (int i = tid; i < 160*YW; i += 256){
        int row = i >> 4, zi = i & 15;
        if (zb + zi < KP) data[tbase + (size_t)row*KP + zi] = f2h(tile[row*17 + zi]);
    }
}

// ---------------- x-axis kernels with analytic K (W=8, round-9 form) ----------------
// spread: one block per (iy, zb). Shared fwd-x FFT once, then per radius:
// scale K_r/160, ilinefft_perm (registers), column-private write, coop store C_r.
__global__ __launch_bounds__(256) void fft_xK(RPc P, const __half2* __restrict__ in)
{
    __shared__ float2 tile[NN][WZ+1];
    int b = blockIdx.x;
    int iy = b % 160, zb = (b / 160) * WZ;
    size_t tbase = (size_t)iy*KP + zb;
    int tid = threadIdx.x, l = tid & 31, q = tid >> 5;
    for (int i = tid; i < NN*WZ; i += 256){
        int row = i >> 3, zi = i & 7;
        tile[row][zi] = (zb + zi < KP) ? h2f(in[tbase + (size_t)row*XS + zi]) : make_float2(0.f,0.f);
    }
    __syncthreads();
    float fy = (float)((iy < 80) ? iy : iy - 160) * (1.f/160.f);
    float fy2 = fy*fy;
    float cy1 = fcos_rev(fy);
    float cy2 = 2.f*cy1*cy1 - 1.f;
    float cy3 = 2.f*cy1*cy2 - cy1;
    QCol qc = make_qcol(1.f, 2.f*cy1, 2.f*cy2, 2.f*cy3, zb + q);
    int o5 = 5*br5(l);
    float2 spec[5];
    #pragma unroll
    for (int n1=0;n1<5;n1++) spec[n1] = tile[n1*32 + l][q];
    linefft<1>(spec, l);
    float K3[5][3];
    #pragma unroll
    for (int k=0;k<5;k++) kval3(qc, fy2, o5+k, K3[k]);
    #pragma unroll
    for (int r=0; r<3; r++){
        float2 acc[5];
        #pragma unroll
        for (int k=0;k<5;k++) acc[k] = cscale(spec[k], K3[k][r] * SC160);
        ilinefft_perm(acc, l);
        // column q is group-private between coop phases
        #pragma unroll
        for (int n1=0;n1<5;n1++) tile[n1*32 + l][q] = acc[n1];
        __syncthreads();
        __half2* Cr = P.C[r];
        for (int i = tid; i < NN*WZ; i += 256){
            int row = i >> 3, zi = i & 7;
            if (zb + zi < KP) Cr[tbase + (size_t)row*XS + zi] = f2h(tile[row][zi]);
        }
        __syncthreads();
    }
}

// gather: CF = invx( sum_r (K_r/160) * fwdx(C_r) ), single tile + reg staging
__global__ __launch_bounds__(256) void fft_xgather(RPc P, __half2* __restrict__ out)
{
    __shared__ float2 tile[NN][WZ+1];
    int b = blockIdx.x;
    int iy = b % 160, zb = (b / 160) * WZ;
    size_t tbase = (size_t)iy*KP + zb;
    int tid = threadIdx.x, l = tid & 31, q = tid >> 5;
    // cooperative load C0 -> tile
    #pragma unroll
    for (int j=0;j<5;j++){
        int i = tid + 256*j;
        int row = i >> 3, zi = i & 7;
        tile[row][zi] = (zb + zi < KP) ? h2f(P.C[0][tbase + (size_t)row*XS + zi]) : make_float2(0.f,0.f);
    }
    __syncthreads();
    float fy = (float)((iy < 80) ? iy : iy - 160) * (1.f/160.f);
    float fy2 = fy*fy;
    float cy1 = fcos_rev(fy);
    float cy2 = 2.f*cy1*cy1 - 1.f;
    float cy3 = 2.f*cy1*cy2 - cy1;
    QCol qc = make_qcol(1.f, 2.f*cy1, 2.f*cy2, 2.f*cy3, zb + q);
    int o5 = 5*br5(l);
    float K3[5][3];
    #pragma unroll
    for (int k=0;k<5;k++) kval3(qc, fy2, o5+k, K3[k]);

    // issue C1 loads early (hide under FFT of C0)
    float2 st[5];
    #pragma unroll
    for (int j=0;j<5;j++){
        int i = tid + 256*j;
        int row = i >> 3, zi = i & 7;
        st[j] = (zb + zi < KP) ? h2f(P.C[1][tbase + (size_t)row*XS + zi]) : make_float2(0.f,0.f);
    }
    float2 y[5], acc[5];
    #pragma unroll
    for (int n1=0;n1<5;n1++) y[n1] = tile[n1*32 + l][q];
    linefft<1>(y, l);
    #pragma unroll
    for (int k=0;k<5;k++) acc[k] = cscale(y[k], K3[k][0] * SC160);
    __syncthreads();
    // write staged C1, issue C2 loads
    #pragma unroll
    for (int j=0;j<5;j++){
        int i = tid + 256*j;
        tile[i >> 3][i & 7] = st[j];
    }
    __syncthreads();
    #pragma unroll
    for (int j=0;j<5;j++){
        int i = tid + 256*j;
        int row = i >> 3, zi = i & 7;
        st[j] = (zb + zi < KP) ? h2f(P.C[2][tbase + (size_t)row*XS + zi]) : make_float2(0.f,0.f);
    }
    #pragma unroll
    for (int n1=0;n1<5;n1++) y[n1] = tile[n1*32 + l][q];
    linefft<1>(y, l);
    #pragma unroll
    for (int k=0;k<5;k++) acc[k] = cadd(acc[k], cscale(y[k], K3[k][1] * SC160));
    __syncthreads();
    #pragma unroll
    for (int j=0;j<5;j++){
        int i = tid + 256*j;
        tile[i >> 3][i & 7] = st[j];
    }
    __syncthreads();
    #pragma unroll
    for (int n1=0;n1<5;n1++) y[n1] = tile[n1*32 + l][q];
    linefft<1>(y, l);
    #pragma unroll
    for (int k=0;k<5;k++) acc[k] = cadd(acc[k], cscale(y[k], K3[k][2] * SC160));
    ilinefft_perm(acc, l);
    __syncthreads();
    #pragma unroll
    for (int n1=0;n1<5;n1++) tile[n1*32 + l][q] = acc[n1];
    __syncthreads();
    for (int i = tid; i < NN*WZ; i += 256){
        int row = i >> 3, zi = i & 7;
        if (zb + zi < KP) out[tbase + (size_t)row*XS + zi] = f2h(tile[row][zi]);
    }
}

// ---------------- setup / CG vector ops ----------------
__global__ __launch_bounds__(256) void m2w_kernel(const float* __restrict__ mask,
        const float* __restrict__ w, __half* __restrict__ M0,
        __half* __restrict__ M1, __half* __restrict__ M2)
{
    int i = blockIdx.x*256 + threadIdx.x;
    float m = mask[i]; float mm = m*m;
    M0[i] = __float2half(mm * w[3*(size_t)i+0]);
    M1[i] = __float2half(mm * w[3*(size_t)i+1]);
    M2[i] = __float2half(mm * w[3*(size_t)i+2]);
}

__global__ __launch_bounds__(256) void copy_kernel(const float* __restrict__ a, float* __restrict__ b){
    int i = blockIdx.x*256 + threadIdx.x;
    b[i] = a[i];
}

#define GSTRIDE (2048*256)
__global__ __launch_bounds__(256) void upd1_kernel(float* __restrict__ x, float* __restrict__ r,
        const float* __restrict__ p, const float* __restrict__ Ap, double* s)
{
    float alpha = (float)(s[0] / (s[1] + 1e-12));
    double acc = 0.0;
    for (int i = blockIdx.x*256 + threadIdx.x; i < N3; i += GSTRIDE){
        x[i] += alpha * p[i];
        float rn = r[i] - alpha * Ap[i];
        r[i] = rn;
        acc += (double)rn * (double)rn;
    }
    block_atomic_add(acc, &s[2]);
}
__global__ void advance_kernel(double* s){
    if (threadIdx.x == 0){
        s[3] = s[2] / (s[0] + 1e-12);   // beta
        s[0] = s[2]; s[1] = 0.0; s[2] = 0.0;
    }
}
__global__ void zero_kernel(double* s){
    if (threadIdx.x < 4) s[threadIdx.x] = 0.0;
}

// ---------------- host orchestration ----------------
extern "C" void kernel_launch(void* const* d_in, const int* in_sizes, int n_in,
                              void* d_out, int out_size, void* d_ws, size_t ws_size,
                              hipStream_t stream)
{
    (void)in_sizes; (void)n_in; (void)out_size;
    const float* w    = (const float*)d_in[0];   // [N3*3], R fastest
    const float* x2   = (const float*)d_in[1];   // [N3]
    const float* mask = (const float*)d_in[2];   // [N3]
    const float* bb   = (const float*)d_in[3];   // [N3]
    float* x = (float*)d_out;
    char* ws = (char*)d_ws;

    size_t off = 0;
    auto alloc = [&](size_t bytes)->void*{
        void* pp = ws + off;
        off += (bytes + 255) & ~(size_t)255;
        return pp;
    };
    const size_t CB = (size_t)NLINES * KP * sizeof(__half2);   // 8.3 MB
    __half2* CF = (__half2*)alloc(CB);
    __half2* C0 = (__half2*)alloc(CB);
    __half2* C1 = (__half2*)alloc(CB);
    __half2* C2 = (__half2*)alloc(CB);
    float*  rr = (float*) alloc((size_t)N3*4);
    float*  pp = (float*) alloc((size_t)N3*4);
    float*  Ap = (float*) alloc((size_t)N3*4);
    double* S  = (double*)alloc(64);
    bool PRE = (ws_size >= off + 3*(((size_t)N3*2 + 255) & ~(size_t)255));
    __half *M0=nullptr, *M1=nullptr, *M2=nullptr;
    if (PRE){
        M0 = (__half*)alloc((size_t)N3*2);
        M1 = (__half*)alloc((size_t)N3*2);
        M2 = (__half*)alloc((size_t)N3*2);
    }
    RPc P;
    P.C[0]=C0; P.C[1]=C1; P.C[2]=C2;
    P.M[0]=M0; P.M[1]=M1; P.M[2]=M2;

    zero_kernel<<<1, 64, 0, stream>>>(S);
    if (PRE) m2w_kernel<<<16000, 256, 0, stream>>>(mask, w, M0, M1, M2);
    copy_kernel<<<16000, 256, 0, stream>>>(x2, x);

    const int GX = NBZ * 160;    // 1760 (x kernels, W=8)
    const int GYW = NBY * 160;   // 960  (y kernels, W=16)
    // PM: 0 = plain fft of z; 1 = fused p-update. FIN: 1 = initial residual, 0 = CG iter.
    auto applyM = [&](const float* z, int FIN, int PM){
        if (PM) fft_z_first<1><<<1600, 256, 0, stream>>>(z, rr, pp, CF, S);
        else    fft_z_first<0><<<1600, 256, 0, stream>>>(z, rr, pp, CF, S);
        fft_y1<1><<<GYW, 256, 0, stream>>>(CF);
        fft_xK<<<GX, 256, 0, stream>>>(P, CF);
        fft_y3<-1><<<dim3(GYW,3), 256, 0, stream>>>(P);
        if (PRE) fft_z_mid3<true ><<<dim3(1600,3), 256, 0, stream>>>(P, mask, w);
        else     fft_z_mid3<false><<<dim3(1600,3), 256, 0, stream>>>(P, mask, w);
        fft_y3<1><<<dim3(GYW,3), 256, 0, stream>>>(P);
        fft_xgather<<<GX, 256, 0, stream>>>(P, CF);
        fft_y1<-1><<<GYW, 256, 0, stream>>>(CF);
        if (FIN) fft_z_fin<1><<<1600, 256, 0, stream>>>(CF, x, Ap, bb, rr, pp, S);
        else     fft_z_fin<0><<<1600, 256, 0, stream>>>(CF, pp, Ap, bb, rr, pp, S);
    };

    // r = b - M(x2); p = r; rs = <r,r>
    applyM(x, 1, 0);

    for (int it = 0; it < 10; it++){
        applyM(pp, 0, (it == 0) ? 0 : 1);          // Ap = M(p), S[1] = <p,Ap>
        upd1_kernel<<<2048, 256, 0, stream>>>(x, rr, pp, Ap, S);
        if (it < 9) advance_kernel<<<1, 64, 0, stream>>>(S);
    }
}

// Round 12
// 2579.290 us; speedup vs baseline: 1.5156x; 1.0758x over previous
//
#include <hip/hip_runtime.h>
#include <hip/hip_fp16.h>

#define NN 160
#define KP 81                // kept kz planes (Hermitian half)
#define N3 4096000           // 160^3
#define NLINES 25600         // 160^2 z-lines
#define WZ 8                 // tile width (kz columns) for x/y sweeps
#define NBZ 11               // ceil(81/8)
#define XS 12960             // x-stride in complex layout (160*81)
#define TPI 6.28318530717958647692f
#define LAM_F 0.05f
#define SC160 (1.f/160.f)

// ---------------- complex helpers ----------------
__device__ __forceinline__ float2 cxmul(float2 a, float2 b){
    return make_float2(a.x*b.x - a.y*b.y, a.x*b.y + a.y*b.x);
}
__device__ __forceinline__ float2 cadd(float2 a, float2 b){ return make_float2(a.x+b.x, a.y+b.y); }
__device__ __forceinline__ float2 csub(float2 a, float2 b){ return make_float2(a.x-b.x, a.y-b.y); }
__device__ __forceinline__ float2 cscale(float2 a, float s){ return make_float2(a.x*s, a.y*s); }
__device__ __forceinline__ float2 shfl2(float2 v, int m){
    return make_float2(__shfl_xor(v.x, m, 64), __shfl_xor(v.y, m, 64));
}
__device__ __forceinline__ int br5(int l){
    return ((l&1)<<4)|((l&2)<<2)|(l&4)|((l&8)>>2)|((l&16)>>4);
}
__device__ __forceinline__ float2 h2f(__half2 h){ return __half22float2(h); }
__device__ __forceinline__ __half2 f2h(float2 f){ return __float22half2_rn(f); }
// rev in revolutions (angle/2pi). v_sin_f32/v_cos_f32 are revolution-input
// on gfx950 -> 1 instr each, no range reduction needed.
__device__ __forceinline__ float fsin_rev(float rev){ return __builtin_amdgcn_sinf(rev); }
__device__ __forceinline__ float fcos_rev(float rev){ return __builtin_amdgcn_cosf(rev); }
template<int SGN>
__device__ __forceinline__ float2 twid(float rev){
    float s = fsin_rev(rev), c = fcos_rev(rev);
    return make_float2(c, (SGN>0) ? -s : s);
}

// ---------------- radix-5 DFT ----------------
template<int SGN>
__device__ __forceinline__ void dft5(float2 y[5]){
    const float C1 = 0.30901699437494742f;
    const float C2 = -0.80901699437494742f;
    const float S1 = 0.95105651629515357f;
    const float S2 = 0.58778525229247312f;
    float2 x0=y[0], x1=y[1], x2=y[2], x3=y[3], x4=y[4];
    float2 t1=cadd(x1,x4), t2=cadd(x2,x3), t3=csub(x1,x4), t4=csub(x2,x3);
    y[0] = cadd(x0, cadd(t1,t2));
    float2 a1 = make_float2(x0.x + C1*t1.x + C2*t2.x, x0.y + C1*t1.y + C2*t2.y);
    float2 a2 = make_float2(x0.x + C2*t1.x + C1*t2.x, x0.y + C2*t1.y + C1*t2.y);
    const float sg = (SGN>0) ? 1.f : -1.f;
    float2 b1 = make_float2(sg*(S1*t3.x + S2*t4.x), sg*(S1*t3.y + S2*t4.y));
    float2 b2 = make_float2(sg*(S2*t3.x - S1*t4.x), sg*(S2*t3.y - S1*t4.y));
    y[1] = make_float2(a1.x + b1.y, a1.y - b1.x);
    y[4] = make_float2(a1.x - b1.y, a1.y + b1.x);
    y[2] = make_float2(a2.x + b2.y, a2.y - b2.x);
    y[3] = make_float2(a2.x - b2.y, a2.y + b2.x);
}

__device__ __forceinline__ float2 bfly(float2 v, int m, float2 tw, int l){
    float2 o = shfl2(v, m);
    float2 s = cadd(v, o);
    float2 d = cxmul(csub(o, v), tw);
    return (l & m) ? d : s;
}

// 160-pt FFT: lane l in [0,32) holds y[n1]=x[n1*32+l] on entry.
// On exit, slot k holds X[k + 5*br5(l)].
template<int SGN>
__device__ __forceinline__ void linefft(float2 y[5], int l){
    dft5<SGN>(y);
    float2 w1 = twid<SGN>((float)l * (1.f/160.f));
    float2 w2 = cxmul(w1,w1);
    float2 w3 = cxmul(w2,w1);
    float2 w4 = cxmul(w2,w2);
    y[1]=cxmul(y[1],w1); y[2]=cxmul(y[2],w2); y[3]=cxmul(y[3],w3); y[4]=cxmul(y[4],w4);
    float2 tw16 = twid<SGN>((float)(l & 15) * (1.f/32.f));
    float2 tw8  = twid<SGN>((float)(l & 7)  * (1.f/16.f));
    float2 tw4  = twid<SGN>((float)(l & 3)  * (1.f/8.f));
    float2 tw2  = twid<SGN>((float)(l & 1)  * (1.f/4.f));
    #pragma unroll
    for (int k=0;k<5;k++){
        float2 v = y[k];
        v = bfly(v,16,tw16,l);
        v = bfly(v, 8,tw8 ,l);
        v = bfly(v, 4,tw4 ,l);
        v = bfly(v, 2,tw2 ,l);
        float2 o = shfl2(v,1);
        v = (l&1) ? csub(o,v) : cadd(v,o);
        y[k] = v;
    }
}

// DIT butterfly: low lane: v + tw*o ; high lane: o - tw*v
__device__ __forceinline__ float2 bflyi(float2 v, int m, float2 tw, int l){
    float2 o = shfl2(v, m);
    float2 t = cxmul(tw, (l & m) ? v : o);
    return (l & m) ? csub(o, t) : cadd(v, t);
}

// inverse 160-pt FFT consuming the forward's permuted register layout:
// entry: slot k lane l = X[k + 5*br5(l)]; exit: y[n1] = x[n1*32+l] (UNscaled).
__device__ __forceinline__ void ilinefft_perm(float2 y[5], int l){
    float2 tw2  = twid<-1>((float)(l & 1)  * (1.f/4.f));
    float2 tw4  = twid<-1>((float)(l & 3)  * (1.f/8.f));
    float2 tw8  = twid<-1>((float)(l & 7)  * (1.f/16.f));
    float2 tw16 = twid<-1>((float)(l & 15) * (1.f/32.f));
    #pragma unroll
    for (int k=0;k<5;k++){
        float2 v = y[k];
        { float2 o = shfl2(v,1); v = (l&1) ? csub(o,v) : cadd(v,o); }
        v = bflyi(v, 2, tw2 , l);
        v = bflyi(v, 4, tw4 , l);
        v = bflyi(v, 8, tw8 , l);
        v = bflyi(v,16, tw16, l);
        y[k] = v;
    }
    float2 w1 = twid<-1>((float)l * (1.f/160.f));
    float2 w2 = cxmul(w1,w1);
    float2 w3 = cxmul(w2,w1);
    float2 w4 = cxmul(w2,w2);
    y[1]=cxmul(y[1],w1); y[2]=cxmul(y[2],w2); y[3]=cxmul(y[3],w3); y[4]=cxmul(y[4],w4);
    dft5<-1>(y);
}

struct RPc {
    __half2* C[3];
    const __half* M[3];
};

// analytic kernel ingredients: Q sums over (dy,dz) ball slices, per column
struct QCol {
    float Q1_0, Q1_1;
    float Q2_0, Q2_1, Q2_2;
    float Q3_0, Q3_1, Q3_2, Q3_3;
    float fz2;
};

__device__ __forceinline__ QCol make_qcol(float ay0,float ay1,float ay2,float ay3, int kz){
    float fz = (float)kz * (1.f/160.f);
    float cz1 = fcos_rev(fz);
    float cz2 = 2.f*cz1*cz1 - 1.f;
    float cz3 = 2.f*cz1*cz2 - cz1;
    float az0=1.f, az1=2.f*cz1, az2=2.f*cz2, az3=2.f*cz3;
    float P00=ay0*az0, P01=ay0*az1, P02=ay0*az2, P03=ay0*az3;
    float P10=ay1*az0, P11=ay1*az1, P12=ay1*az2;
    float P20=ay2*az0, P21=ay2*az1, P22=ay2*az2;
    float P30=ay3*az0;
    QCol q;
    q.Q1_0 = P00 + P01 + P10;
    q.Q1_1 = P00;
    q.Q2_0 = P00+P01+P02+P10+P11+P20;
    q.Q2_1 = P00+P01+P10+P11;
    q.Q2_2 = P00;
    q.Q3_0 = P00+P01+P02+P03+P10+P11+P12+P20+P21+P22+P30;
    q.Q3_1 = P00+P01+P02+P10+P11+P12+P20+P21+P22;
    q.Q3_2 = P00+P01+P02+P10+P11+P12+P20+P21;
    q.Q3_3 = P00;
    q.fz2 = fz*fz;
    return q;
}

// all three K_r with one cosine chain. kx in [0,160).
__device__ __forceinline__ void kval3(const QCol& q, float fy2, int kx, float K[3]){
    float c1 = fcos_rev((float)kx * (1.f/160.f));
    float c2 = 2.f*c1*c1 - 1.f;
    float c3 = 2.f*c1*c2 - c1;
    float s1 = (q.Q1_0 + 2.f*c1*q.Q1_1) * (1.f/7.f);
    float s2 = (q.Q2_0 + 2.f*(c1*q.Q2_1 + c2*q.Q2_2)) * (1.f/33.f);
    float s3 = (q.Q3_0 + 2.f*(c1*q.Q3_1 + c2*q.Q3_2 + c3*q.Q3_3)) * (1.f/123.f);
    float fxw = (float)((kx < 80) ? kx : 160 - kx) * (1.f/160.f);
    float k2 = fxw*fxw + fy2 + q.fz2;
    float D = (1.f/3.f) - ((k2 == 0.f) ? 0.f : q.fz2 * __builtin_amdgcn_rcpf(k2));
    K[0] = (1.f - s1) * D;
    K[1] = (1.f - s2) * D;
    K[2] = (1.f - s3) * D;
}

// ---------------- CG reduction helper ----------------
__device__ __forceinline__ void block_atomic_add(double v, double* target){
    #pragma unroll
    for (int off=32; off>0; off>>=1) v += __shfl_down(v, off, 64);
    __shared__ double sm[4];
    int wv = threadIdx.x >> 6;
    if ((threadIdx.x & 63) == 0) sm[wv] = v;
    __syncthreads();
    if (threadIdx.x == 0) atomicAdd(target, sm[0]+sm[1]+sm[2]+sm[3]);
}

// ======== z-axis kernels: wave-local, barrier-free ========
// Forward passes carry 1/160 each axis; inverse passes are UNscaled.
// PM=0: fft real zin. PM=1: p = r + beta*p (beta=S[3]), store p, fft p.
template<int PM>
__global__ __launch_bounds__(256) void fft_z_first(const float* __restrict__ zin,
    const float* __restrict__ rrv, float* __restrict__ ppv,
    __half2* __restrict__ out, const double* __restrict__ S)
{
    __shared__ float2 ldsC[8*162];
    int tid = threadIdx.x, l = tid & 31, g = tid >> 5;
    int fl = g*162;
    size_t base160 = (size_t)blockIdx.x * 2560 + (size_t)(2*g)*160;
    size_t baseC   = (size_t)blockIdx.x * 1296 + (size_t)g*162;
    float beta = PM ? (float)S[3] : 0.f;
    float2 y[5];
    #pragma unroll
    for (int n1=0;n1<5;n1++){
        int n = n1*32 + l;
        float a, b;
        if (PM){
            a = rrv[base160 + n]       + beta * ppv[base160 + n];
            b = rrv[base160 + 160 + n] + beta * ppv[base160 + 160 + n];
            ppv[base160 + n] = a;
            ppv[base160 + 160 + n] = b;
        } else {
            a = zin[base160 + n];
            b = zin[base160 + 160 + n];
        }
        y[n1] = make_float2(a * SC160, b * SC160);   // fwd 1/160
    }
    linefft<1>(y, l);
    int o5 = 5*br5(l);
    #pragma unroll
    for (int k=0;k<5;k++) ldsC[fl + o5 + k] = y[k];
    #pragma unroll
    for (int t=0;t<6;t++){
        int j = l + 32*t;
        if (j < 162){
            int k = (j < 81) ? j : j - 81;
            float2 Sk = ldsC[fl + k];
            float2 Sm = ldsC[fl + ((160 - k) % 160)];
            float2 o = (j >= 81)
                ? make_float2(0.5f*(Sk.y + Sm.y), -0.5f*(Sk.x - Sm.x))    // B
                : make_float2(0.5f*(Sk.x + Sm.x),  0.5f*(Sk.y - Sm.y));   // A
            out[baseC + j] = f2h(o);
        }
    }
}

// fused: inverse-z (unscaled) -> *(m2w_r/160) -> forward-z
template<bool PRE>
__global__ __launch_bounds__(256) void fft_z_mid3(RPc P, const float* __restrict__ mask,
                                                 const float* __restrict__ wfull)
{
    __shared__ float2 ldsC[8*162];
    int r = blockIdx.y;
    __half2* C = P.C[r];
    int tid = threadIdx.x, l = tid & 31, g = tid >> 5;
    int fl = g*162;
    size_t baseC   = (size_t)blockIdx.x * 1296 + (size_t)g*162;
    size_t base160 = (size_t)blockIdx.x * 2560 + (size_t)(2*g)*160;
    int o5 = 5*br5(l);
    float ma[5], mb[5];
    if (PRE){
        const __half* M = P.M[r];
        #pragma unroll
        for (int k=0;k<5;k++){
            ma[k] = __half2float(M[base160 + o5 + k]) * SC160;
            mb[k] = __half2float(M[base160 + 160 + o5 + k]) * SC160;
        }
    } else {
        #pragma unroll
        for (int k=0;k<5;k++){
            size_t ia = base160 + o5 + k, ib = base160 + 160 + o5 + k;
            float m1 = mask[ia], m2 = mask[ib];
            ma[k] = m1*m1*wfull[ia*3 + r] * SC160;
            mb[k] = m2*m2*wfull[ib*3 + r] * SC160;
        }
    }
    #pragma unroll
    for (int t=0;t<6;t++){
        int j = l + 32*t;
        if (j < 162) ldsC[fl + j] = h2f(C[baseC + j]);
    }
    float2 y[5];
    #pragma unroll
    for (int n1=0;n1<5;n1++){
        int e = n1*32 + l;
        float2 X;
        if (e <= 80){
            float2 A = ldsC[fl + e], B = ldsC[fl + 81 + e];
            X = make_float2(A.x - B.y, A.y + B.x);
        } else {
            int m = 160 - e;
            float2 A = ldsC[fl + m], B = ldsC[fl + 81 + m];
            X = make_float2(A.x + B.y, B.x - A.y);
        }
        y[n1] = X;
    }
    linefft<-1>(y, l);
    #pragma unroll
    for (int k=0;k<5;k++){
        float a = y[k].x * ma[k];
        float b = y[k].y * mb[k];
        ldsC[fl + o5 + k] = make_float2(a, b);
    }
    #pragma unroll
    for (int n1=0;n1<5;n1++) y[n1] = ldsC[fl + n1*32 + l];
    linefft<1>(y, l);
    #pragma unroll
    for (int k=0;k<5;k++) ldsC[fl + o5 + k] = y[k];
    #pragma unroll
    for (int t=0;t<6;t++){
        int j = l + 32*t;
        if (j < 162){
            int k = (j < 81) ? j : j - 81;
            float2 Sk = ldsC[fl + k];
            float2 Sm = ldsC[fl + ((160 - k) % 160)];
            float2 o = (j >= 81)
                ? make_float2(0.5f*(Sk.y + Sm.y), -0.5f*(Sk.x - Sm.x))
                : make_float2(0.5f*(Sk.x + Sm.x),  0.5f*(Sk.y - Sm.y));
            C[baseC + j] = f2h(o);
        }
    }
}

// final inverse-z (unscaled) + epilogue.
// FIN=0: Ap=v, S[1]+=<z,v>. FIN=1: r=b-v -> rr,pp, S[0]+=<r,r>.
template<int FIN>
__global__ __launch_bounds__(256) void fft_z_fin(const __half2* __restrict__ in,
    const float* __restrict__ zsp, float* __restrict__ Ap,
    const float* __restrict__ bb, float* __restrict__ rrv, float* __restrict__ ppv,
    double* __restrict__ S)
{
    __shared__ float2 ldsC[8*162];
    float* ldsF = (float*)ldsC;      // region g: floats [324g, 324g+320)
    int tid = threadIdx.x, l = tid & 31, g = tid >> 5;
    int fl = g*162;
    size_t baseC   = (size_t)blockIdx.x * 1296 + (size_t)g*162;
    size_t base160 = (size_t)blockIdx.x * 2560 + (size_t)(2*g)*160;
    int o5 = 5*br5(l);
    float za[5], zb[5], pa[5], pb[5];
    #pragma unroll
    for (int k=0;k<5;k++){
        za[k] = zsp[base160 + o5 + k];
        zb[k] = zsp[base160 + 160 + o5 + k];
        if (FIN){
            pa[k] = bb[base160 + o5 + k];
            pb[k] = bb[base160 + 160 + o5 + k];
        }
    }
    #pragma unroll
    for (int t=0;t<6;t++){
        int j = l + 32*t;
        if (j < 162) ldsC[fl + j] = h2f(in[baseC + j]);
    }
    float2 y[5];
    #pragma unroll
    for (int n1=0;n1<5;n1++){
        int e = n1*32 + l;
        float2 X;
        if (e <= 80){
            float2 A = ldsC[fl + e], B = ldsC[fl + 81 + e];
            X = make_float2(A.x - B.y, A.y + B.x);
        } else {
            int m = 160 - e;
            float2 A = ldsC[fl + m], B = ldsC[fl + 81 + m];
            X = make_float2(A.x + B.y, B.x - A.y);
        }
        y[n1] = X;
    }
    linefft<-1>(y, l);
    double acc = 0.0;
    int fb = g*324;
    #pragma unroll
    for (int k=0;k<5;k++){
        float va = LAM_F*za[k] + y[k].x;      // inverse unscaled
        float vb = LAM_F*zb[k] + y[k].y;
        if (FIN == 0){
            acc += (double)za[k]*(double)va + (double)zb[k]*(double)vb;
            ldsF[fb + o5 + k] = va;
            ldsF[fb + 160 + o5 + k] = vb;
        } else {
            float ra = pa[k] - va, rb = pb[k] - vb;
            acc += (double)ra*(double)ra + (double)rb*(double)rb;
            ldsF[fb + o5 + k] = ra;
            ldsF[fb + 160 + o5 + k] = rb;
        }
    }
    #pragma unroll
    for (int t=0;t<10;t++){
        int n = l + 32*t;
        float v = ldsF[fb + n];
        if (FIN == 0){
            Ap[base160 + n] = v;
        } else {
            rrv[base160 + n] = v;
            ppv[base160 + n] = v;
        }
    }
    block_atomic_add(acc, FIN ? &S[0] : &S[1]);
}

// ---------------- y-axis sweeps (strided, guarded half-spectrum, W=8) ----------------
// SGN>0 (fwd): scale 1/160 ; SGN<0 (inv): unscaled.
template<int SGN>
__device__ __forceinline__ void ycompute(float2 (*tile)[WZ+1], int tid){
    int l = tid & 31, q = tid >> 5;
    const float SC = (SGN>0) ? SC160 : 1.f;
    float2 y[5];
    #pragma unroll
    for (int n1=0;n1<5;n1++) y[n1] = tile[l + 32*n1][q];
    linefft<SGN>(y, l);
    int o5 = 5*br5(l);
    #pragma unroll
    for (int k=0;k<5;k++) tile[o5+k][q] = cscale(y[k], SC);
}

// b = zchunk*160 + ix  (zb-outer so line-sharing blocks b, b+160 share an XCD)
template<int SGN>
__global__ __launch_bounds__(256) void fft_y1(__half2* __restrict__ data)
{
    __shared__ float2 tile[NN][WZ+1];
    int b = blockIdx.x;
    int ix = b % 160, zb = (b / 160) * WZ;
    size_t tbase = (size_t)ix*XS + zb;
    int tid = threadIdx.x;
    for (int i = tid; i < NN*WZ; i += 256){
        int row = i >> 3, zi = i & 7;
        tile[row][zi] = (zb + zi < KP) ? h2f(data[tbase + (size_t)row*KP + zi]) : make_float2(0.f,0.f);
    }
    __syncthreads();
    ycompute<SGN>(tile, tid);
    __syncthreads();
    for (int i = tid; i < NN*WZ; i += 256){
        int row = i >> 3, zi = i & 7;
        if (zb + zi < KP) data[tbase + (size_t)row*KP + zi] = f2h(tile[row][zi]);
    }
}

template<int SGN>
__global__ __launch_bounds__(256) void fft_y3(RPc P)
{
    __shared__ float2 tile[NN][WZ+1];
    __half2* data = P.C[blockIdx.y];
    int b = blockIdx.x;
    int ix = b % 160, zb = (b / 160) * WZ;
    size_t tbase = (size_t)ix*XS + zb;
    int tid = threadIdx.x;
    for (int i = tid; i < NN*WZ; i += 256){
        int row = i >> 3, zi = i & 7;
        tile[row][zi] = (zb + zi < KP) ? h2f(data[tbase + (size_t)row*KP + zi]) : make_float2(0.f,0.f);
    }
    __syncthreads();
    ycompute<SGN>(tile, tid);
    __syncthreads();
    for (int i = tid; i < NN*WZ; i += 256){
        int row = i >> 3, zi = i & 7;
        if (zb + zi < KP) data[tbase + (size_t)row*KP + zi] = f2h(tile[row][zi]);
    }
}

// ---------------- x-axis kernels with analytic K ----------------
// spread: one block per (iy, zb). GROUP-OWN-COLUMN direct loads (4B/lane;
// the 8 groups of a block touch the same 32B sector -> L2 merges), shared
// fwd-x FFT once in registers, per radius: K_r/160, ilinefft_perm,
// column-private tile write, coop store C_r.
__global__ __launch_bounds__(256) void fft_xK(RPc P, const __half2* __restrict__ in)
{
    __shared__ float2 tile[NN][WZ+1];
    int b = blockIdx.x;
    int iy = b % 160, zb = (b / 160) * WZ;
    size_t tbase = (size_t)iy*KP + zb;
    int tid = threadIdx.x, l = tid & 31, q = tid >> 5;
    bool okc = (zb + q < KP);
    // own-column loads: no barrier, each group independent
    float2 spec[5];
    #pragma unroll
    for (int n1=0;n1<5;n1++){
        int row = n1*32 + l;
        spec[n1] = okc ? h2f(in[tbase + (size_t)row*XS + q]) : make_float2(0.f,0.f);
    }
    float fy = (float)((iy < 80) ? iy : iy - 160) * (1.f/160.f);
    float fy2 = fy*fy;
    float cy1 = fcos_rev(fy);
    float cy2 = 2.f*cy1*cy1 - 1.f;
    float cy3 = 2.f*cy1*cy2 - cy1;
    QCol qc = make_qcol(1.f, 2.f*cy1, 2.f*cy2, 2.f*cy3, zb + q);
    int o5 = 5*br5(l);
    linefft<1>(spec, l);
    float K3[5][3];
    #pragma unroll
    for (int k=0;k<5;k++) kval3(qc, fy2, o5+k, K3[k]);
    #pragma unroll
    for (int r=0; r<3; r++){
        float2 acc[5];
        #pragma unroll
        for (int k=0;k<5;k++) acc[k] = cscale(spec[k], K3[k][r] * SC160);
        ilinefft_perm(acc, l);
        // column q is group-private until the coop store
        #pragma unroll
        for (int n1=0;n1<5;n1++) tile[n1*32 + l][q] = acc[n1];
        __syncthreads();
        __half2* Cr = P.C[r];
        for (int i = tid; i < NN*WZ; i += 256){
            int row = i >> 3, zi = i & 7;
            if (zb + zi < KP) Cr[tbase + (size_t)row*XS + zi] = f2h(tile[row][zi]);
        }
        __syncthreads();
    }
}

// gather: CF = invx( sum_r (K_r/160) * fwdx(C_r) ).
// Fully wave-local (own-column loads for all three C_r, accumulate in regs),
// ONE barrier before the final coalesced store-transpose.
__global__ __launch_bounds__(256) void fft_xgather(RPc P, __half2* __restrict__ out)
{
    __shared__ float2 tile[NN][WZ+1];
    int b = blockIdx.x;
    int iy = b % 160, zb = (b / 160) * WZ;
    size_t tbase = (size_t)iy*KP + zb;
    int tid = threadIdx.x, l = tid & 31, q = tid >> 5;
    bool okc = (zb + q < KP);
    float fy = (float)((iy < 80) ? iy : iy - 160) * (1.f/160.f);
    float fy2 = fy*fy;
    float cy1 = fcos_rev(fy);
    float cy2 = 2.f*cy1*cy1 - 1.f;
    float cy3 = 2.f*cy1*cy2 - cy1;
    QCol qc = make_qcol(1.f, 2.f*cy1, 2.f*cy2, 2.f*cy3, zb + q);
    int o5 = 5*br5(l);
    float K3[5][3];
    #pragma unroll
    for (int k=0;k<5;k++) kval3(qc, fy2, o5+k, K3[k]);
    float2 acc[5];
    #pragma unroll
    for (int k=0;k<5;k++) acc[k] = make_float2(0.f,0.f);
    #pragma unroll
    for (int r=0; r<3; r++){
        const __half2* Cr = P.C[r];
        float2 y[5];
        #pragma unroll
        for (int n1=0;n1<5;n1++){
            int row = n1*32 + l;
            y[n1] = okc ? h2f(Cr[tbase + (size_t)row*XS + q]) : make_float2(0.f,0.f);
        }
        linefft<1>(y, l);
        #pragma unroll
        for (int k=0;k<5;k++) acc[k] = cadd(acc[k], cscale(y[k], K3[k][r] * SC160));
    }
    ilinefft_perm(acc, l);
    #pragma unroll
    for (int n1=0;n1<5;n1++) tile[n1*32 + l][q] = acc[n1];
    __syncthreads();
    for (int i = tid; i < NN*WZ; i += 256){
        int row = i >> 3, zi = i & 7;
        if (zb + zi < KP) out[tbase + (size_t)row*XS + zi] = f2h(tile[row][zi]);
    }
}

// ---------------- setup / CG vector ops ----------------
__global__ __launch_bounds__(256) void m2w_kernel(const float* __restrict__ mask,
        const float* __restrict__ w, __half* __restrict__ M0,
        __half* __restrict__ M1, __half* __restrict__ M2)
{
    int i = blockIdx.x*256 + threadIdx.x;
    float m = mask[i]; float mm = m*m;
    M0[i] = __float2half(mm * w[3*(size_t)i+0]);
    M1[i] = __float2half(mm * w[3*(size_t)i+1]);
    M2[i] = __float2half(mm * w[3*(size_t)i+2]);
}

__global__ __launch_bounds__(256) void copy_kernel(const float* __restrict__ a, float* __restrict__ b){
    int i = blockIdx.x*256 + threadIdx.x;
    b[i] = a[i];
}

#define GSTRIDE (2048*256)
__global__ __launch_bounds__(256) void upd1_kernel(float* __restrict__ x, float* __restrict__ r,
        const float* __restrict__ p, const float* __restrict__ Ap, double* s)
{
    float alpha = (float)(s[0] / (s[1] + 1e-12));
    double acc = 0.0;
    for (int i = blockIdx.x*256 + threadIdx.x; i < N3; i += GSTRIDE){
        x[i] += alpha * p[i];
        float rn = r[i] - alpha * Ap[i];
        r[i] = rn;
        acc += (double)rn * (double)rn;
    }
    block_atomic_add(acc, &s[2]);
}
__global__ void advance_kernel(double* s){
    if (threadIdx.x == 0){
        s[3] = s[2] / (s[0] + 1e-12);   // beta
        s[0] = s[2]; s[1] = 0.0; s[2] = 0.0;
    }
}
__global__ void zero_kernel(double* s){
    if (threadIdx.x < 4) s[threadIdx.x] = 0.0;
}

// ---------------- host orchestration ----------------
extern "C" void kernel_launch(void* const* d_in, const int* in_sizes, int n_in,
                              void* d_out, int out_size, void* d_ws, size_t ws_size,
                              hipStream_t stream)
{
    (void)in_sizes; (void)n_in; (void)out_size;
    const float* w    = (const float*)d_in[0];   // [N3*3], R fastest
    const float* x2   = (const float*)d_in[1];   // [N3]
    const float* mask = (const float*)d_in[2];   // [N3]
    const float* bb   = (const float*)d_in[3];   // [N3]
    float* x = (float*)d_out;
    char* ws = (char*)d_ws;

    size_t off = 0;
    auto alloc = [&](size_t bytes)->void*{
        void* pp = ws + off;
        off += (bytes + 255) & ~(size_t)255;
        return pp;
    };
    const size_t CB = (size_t)NLINES * KP * sizeof(__half2);   // 8.3 MB
    __half2* CF = (__half2*)alloc(CB);
    __half2* C0 = (__half2*)alloc(CB);
    __half2* C1 = (__half2*)alloc(CB);
    __half2* C2 = (__half2*)alloc(CB);
    float*  rr = (float*) alloc((size_t)N3*4);
    float*  pp = (float*) alloc((size_t)N3*4);
    float*  Ap = (float*) alloc((size_t)N3*4);
    double* S  = (double*)alloc(64);
    bool PRE = (ws_size >= off + 3*(((size_t)N3*2 + 255) & ~(size_t)255));
    __half *M0=nullptr, *M1=nullptr, *M2=nullptr;
    if (PRE){
        M0 = (__half*)alloc((size_t)N3*2);
        M1 = (__half*)alloc((size_t)N3*2);
        M2 = (__half*)alloc((size_t)N3*2);
    }
    RPc P;
    P.C[0]=C0; P.C[1]=C1; P.C[2]=C2;
    P.M[0]=M0; P.M[1]=M1; P.M[2]=M2;

    zero_kernel<<<1, 64, 0, stream>>>(S);
    if (PRE) m2w_kernel<<<16000, 256, 0, stream>>>(mask, w, M0, M1, M2);
    copy_kernel<<<16000, 256, 0, stream>>>(x2, x);

    const int GY = NBZ * 160;    // 1760
    // PM: 0 = plain fft of z; 1 = fused p-update. FIN: 1 = initial residual, 0 = CG iter.
    auto applyM = [&](const float* z, int FIN, int PM){
        if (PM) fft_z_first<1><<<1600, 256, 0, stream>>>(z, rr, pp, CF, S);
        else    fft_z_first<0><<<1600, 256, 0, stream>>>(z, rr, pp, CF, S);
        fft_y1<1><<<GY, 256, 0, stream>>>(CF);
        fft_xK<<<GY, 256, 0, stream>>>(P, CF);
        fft_y3<-1><<<dim3(GY,3), 256, 0, stream>>>(P);
        if (PRE) fft_z_mid3<true ><<<dim3(1600,3), 256, 0, stream>>>(P, mask, w);
        else     fft_z_mid3<false><<<dim3(1600,3), 256, 0, stream>>>(P, mask, w);
        fft_y3<1><<<dim3(GY,3), 256, 0, stream>>>(P);
        fft_xgather<<<GY, 256, 0, stream>>>(P, CF);
        fft_y1<-1><<<GY, 256, 0, stream>>>(CF);
        if (FIN) fft_z_fin<1><<<1600, 256, 0, stream>>>(CF, x, Ap, bb, rr, pp, S);
        else     fft_z_fin<0><<<1600, 256, 0, stream>>>(CF, pp, Ap, bb, rr, pp, S);
    };

    // r = b - M(x2); p = r; rs = <r,r>
    applyM(x, 1, 0);

    for (int it = 0; it < 10; it++){
        applyM(pp, 0, (it == 0) ? 0 : 1);          // Ap = M(p), S[1] = <p,Ap>
        upd1_kernel<<<2048, 256, 0, stream>>>(x, rr, pp, Ap, S);
        if (it < 9) advance_kernel<<<1, 64, 0, stream>>>(S);
    }
}

// Round 13
// 2523.788 us; speedup vs baseline: 1.5489x; 1.0220x over previous
//
#include <hip/hip_runtime.h>
#include <hip/hip_fp16.h>

#define NN 160
#define KP 81                // kept kz planes (Hermitian half)
#define N3 4096000           // 160^3
#define NLINES 25600         // 160^2 z-lines
#define WZ 8                 // tile width (kz columns) for x/y sweeps
#define NBZ 11               // ceil(81/8)
#define XS 12960             // x-stride in complex layout (160*81)
#define TPI 6.28318530717958647692f
#define LAM_F 0.05f
#define SC160 (1.f/160.f)

// ---------------- complex helpers ----------------
__device__ __forceinline__ float2 cxmul(float2 a, float2 b){
    return make_float2(a.x*b.x - a.y*b.y, a.x*b.y + a.y*b.x);
}
__device__ __forceinline__ float2 cadd(float2 a, float2 b){ return make_float2(a.x+b.x, a.y+b.y); }
__device__ __forceinline__ float2 csub(float2 a, float2 b){ return make_float2(a.x-b.x, a.y-b.y); }
__device__ __forceinline__ float2 cscale(float2 a, float s){ return make_float2(a.x*s, a.y*s); }
__device__ __forceinline__ float2 shfl2(float2 v, int m){
    return make_float2(__shfl_xor(v.x, m, 64), __shfl_xor(v.y, m, 64));
}
__device__ __forceinline__ int br5(int l){
    return ((l&1)<<4)|((l&2)<<2)|(l&4)|((l&8)>>2)|((l&16)>>4);
}
__device__ __forceinline__ float2 h2f(__half2 h){ return __half22float2(h); }
__device__ __forceinline__ __half2 f2h(float2 f){ return __float22half2_rn(f); }
// rev in revolutions (angle/2pi). v_sin_f32/v_cos_f32 are revolution-input
// on gfx950 -> 1 instr each, no range reduction needed.
__device__ __forceinline__ float fsin_rev(float rev){ return __builtin_amdgcn_sinf(rev); }
__device__ __forceinline__ float fcos_rev(float rev){ return __builtin_amdgcn_cosf(rev); }
template<int SGN>
__device__ __forceinline__ float2 twid(float rev){
    float s = fsin_rev(rev), c = fcos_rev(rev);
    return make_float2(c, (SGN>0) ? -s : s);
}

// ---------------- radix-5 DFT ----------------
template<int SGN>
__device__ __forceinline__ void dft5(float2 y[5]){
    const float C1 = 0.30901699437494742f;
    const float C2 = -0.80901699437494742f;
    const float S1 = 0.95105651629515357f;
    const float S2 = 0.58778525229247312f;
    float2 x0=y[0], x1=y[1], x2=y[2], x3=y[3], x4=y[4];
    float2 t1=cadd(x1,x4), t2=cadd(x2,x3), t3=csub(x1,x4), t4=csub(x2,x3);
    y[0] = cadd(x0, cadd(t1,t2));
    float2 a1 = make_float2(x0.x + C1*t1.x + C2*t2.x, x0.y + C1*t1.y + C2*t2.y);
    float2 a2 = make_float2(x0.x + C2*t1.x + C1*t2.x, x0.y + C2*t1.y + C1*t2.y);
    const float sg = (SGN>0) ? 1.f : -1.f;
    float2 b1 = make_float2(sg*(S1*t3.x + S2*t4.x), sg*(S1*t3.y + S2*t4.y));
    float2 b2 = make_float2(sg*(S2*t3.x - S1*t4.x), sg*(S2*t3.y - S1*t4.y));
    y[1] = make_float2(a1.x + b1.y, a1.y - b1.x);
    y[4] = make_float2(a1.x - b1.y, a1.y + b1.x);
    y[2] = make_float2(a2.x + b2.y, a2.y - b2.x);
    y[3] = make_float2(a2.x - b2.y, a2.y + b2.x);
}

__device__ __forceinline__ float2 bfly(float2 v, int m, float2 tw, int l){
    float2 o = shfl2(v, m);
    float2 s = cadd(v, o);
    float2 d = cxmul(csub(o, v), tw);
    return (l & m) ? d : s;
}

// 160-pt FFT: lane l in [0,32) holds y[n1]=x[n1*32+l] on entry.
// On exit, slot k holds X[k + 5*br5(l)].
template<int SGN>
__device__ __forceinline__ void linefft(float2 y[5], int l){
    dft5<SGN>(y);
    float2 w1 = twid<SGN>((float)l * (1.f/160.f));
    float2 w2 = cxmul(w1,w1);
    float2 w3 = cxmul(w2,w1);
    float2 w4 = cxmul(w2,w2);
    y[1]=cxmul(y[1],w1); y[2]=cxmul(y[2],w2); y[3]=cxmul(y[3],w3); y[4]=cxmul(y[4],w4);
    float2 tw16 = twid<SGN>((float)(l & 15) * (1.f/32.f));
    float2 tw8  = twid<SGN>((float)(l & 7)  * (1.f/16.f));
    float2 tw4  = twid<SGN>((float)(l & 3)  * (1.f/8.f));
    float2 tw2  = twid<SGN>((float)(l & 1)  * (1.f/4.f));
    #pragma unroll
    for (int k=0;k<5;k++){
        float2 v = y[k];
        v = bfly(v,16,tw16,l);
        v = bfly(v, 8,tw8 ,l);
        v = bfly(v, 4,tw4 ,l);
        v = bfly(v, 2,tw2 ,l);
        float2 o = shfl2(v,1);
        v = (l&1) ? csub(o,v) : cadd(v,o);
        y[k] = v;
    }
}

// DIT butterfly: low lane: v + tw*o ; high lane: o - tw*v
__device__ __forceinline__ float2 bflyi(float2 v, int m, float2 tw, int l){
    float2 o = shfl2(v, m);
    float2 t = cxmul(tw, (l & m) ? v : o);
    return (l & m) ? csub(o, t) : cadd(v, t);
}

// inverse 160-pt FFT consuming the forward's permuted register layout:
// entry: slot k lane l = X[k + 5*br5(l)]; exit: y[n1] = x[n1*32+l] (UNscaled).
__device__ __forceinline__ void ilinefft_perm(float2 y[5], int l){
    float2 tw2  = twid<-1>((float)(l & 1)  * (1.f/4.f));
    float2 tw4  = twid<-1>((float)(l & 3)  * (1.f/8.f));
    float2 tw8  = twid<-1>((float)(l & 7)  * (1.f/16.f));
    float2 tw16 = twid<-1>((float)(l & 15) * (1.f/32.f));
    #pragma unroll
    for (int k=0;k<5;k++){
        float2 v = y[k];
        { float2 o = shfl2(v,1); v = (l&1) ? csub(o,v) : cadd(v,o); }
        v = bflyi(v, 2, tw2 , l);
        v = bflyi(v, 4, tw4 , l);
        v = bflyi(v, 8, tw8 , l);
        v = bflyi(v,16, tw16, l);
        y[k] = v;
    }
    float2 w1 = twid<-1>((float)l * (1.f/160.f));
    float2 w2 = cxmul(w1,w1);
    float2 w3 = cxmul(w2,w1);
    float2 w4 = cxmul(w2,w2);
    y[1]=cxmul(y[1],w1); y[2]=cxmul(y[2],w2); y[3]=cxmul(y[3],w3); y[4]=cxmul(y[4],w4);
    dft5<-1>(y);
}

struct RPc {
    __half2* C[3];
    const __half* M[3];
};

// analytic kernel ingredients: Q sums over (dy,dz) ball slices, per column
struct QCol {
    float Q1_0, Q1_1;
    float Q2_0, Q2_1, Q2_2;
    float Q3_0, Q3_1, Q3_2, Q3_3;
    float fz2;
};

__device__ __forceinline__ QCol make_qcol(float ay0,float ay1,float ay2,float ay3, int kz){
    float fz = (float)kz * (1.f/160.f);
    float cz1 = fcos_rev(fz);
    float cz2 = 2.f*cz1*cz1 - 1.f;
    float cz3 = 2.f*cz1*cz2 - cz1;
    float az0=1.f, az1=2.f*cz1, az2=2.f*cz2, az3=2.f*cz3;
    float P00=ay0*az0, P01=ay0*az1, P02=ay0*az2, P03=ay0*az3;
    float P10=ay1*az0, P11=ay1*az1, P12=ay1*az2;
    float P20=ay2*az0, P21=ay2*az1, P22=ay2*az2;
    float P30=ay3*az0;
    QCol q;
    q.Q1_0 = P00 + P01 + P10;
    q.Q1_1 = P00;
    q.Q2_0 = P00+P01+P02+P10+P11+P20;
    q.Q2_1 = P00+P01+P10+P11;
    q.Q2_2 = P00;
    q.Q3_0 = P00+P01+P02+P03+P10+P11+P12+P20+P21+P22+P30;
    q.Q3_1 = P00+P01+P02+P10+P11+P12+P20+P21+P22;
    q.Q3_2 = P00+P01+P02+P10+P11+P12+P20+P21;
    q.Q3_3 = P00;
    q.fz2 = fz*fz;
    return q;
}

// all three K_r with one cosine chain. kx in [0,160).
__device__ __forceinline__ void kval3(const QCol& q, float fy2, int kx, float K[3]){
    float c1 = fcos_rev((float)kx * (1.f/160.f));
    float c2 = 2.f*c1*c1 - 1.f;
    float c3 = 2.f*c1*c2 - c1;
    float s1 = (q.Q1_0 + 2.f*c1*q.Q1_1) * (1.f/7.f);
    float s2 = (q.Q2_0 + 2.f*(c1*q.Q2_1 + c2*q.Q2_2)) * (1.f/33.f);
    float s3 = (q.Q3_0 + 2.f*(c1*q.Q3_1 + c2*q.Q3_2 + c3*q.Q3_3)) * (1.f/123.f);
    float fxw = (float)((kx < 80) ? kx : 160 - kx) * (1.f/160.f);
    float k2 = fxw*fxw + fy2 + q.fz2;
    float D = (1.f/3.f) - ((k2 == 0.f) ? 0.f : q.fz2 * __builtin_amdgcn_rcpf(k2));
    K[0] = (1.f - s1) * D;
    K[1] = (1.f - s2) * D;
    K[2] = (1.f - s3) * D;
}

// ---------------- CG reduction helper ----------------
__device__ __forceinline__ void block_atomic_add(double v, double* target){
    #pragma unroll
    for (int off=32; off>0; off>>=1) v += __shfl_down(v, off, 64);
    __shared__ double sm[4];
    int wv = threadIdx.x >> 6;
    if ((threadIdx.x & 63) == 0) sm[wv] = v;
    __syncthreads();
    if (threadIdx.x == 0) atomicAdd(target, sm[0]+sm[1]+sm[2]+sm[3]);
}

// ======== z-axis kernels: wave-local, barrier-free ========
// Forward passes carry 1/160 each axis; inverse passes are UNscaled.
// PM=0: fft real zin. PM=1: p = r + beta*p (beta=S[3]), store p, fft p.
template<int PM>
__global__ __launch_bounds__(256) void fft_z_first(const float* __restrict__ zin,
    const float* __restrict__ rrv, float* __restrict__ ppv,
    __half2* __restrict__ out, const double* __restrict__ S)
{
    __shared__ float2 ldsC[8*162];
    int tid = threadIdx.x, l = tid & 31, g = tid >> 5;
    int fl = g*162;
    size_t base160 = (size_t)blockIdx.x * 2560 + (size_t)(2*g)*160;
    size_t baseC   = (size_t)blockIdx.x * 1296 + (size_t)g*162;
    float beta = PM ? (float)S[3] : 0.f;
    float2 y[5];
    #pragma unroll
    for (int n1=0;n1<5;n1++){
        int n = n1*32 + l;
        float a, b;
        if (PM){
            a = rrv[base160 + n]       + beta * ppv[base160 + n];
            b = rrv[base160 + 160 + n] + beta * ppv[base160 + 160 + n];
            ppv[base160 + n] = a;
            ppv[base160 + 160 + n] = b;
        } else {
            a = zin[base160 + n];
            b = zin[base160 + 160 + n];
        }
        y[n1] = make_float2(a * SC160, b * SC160);   // fwd 1/160
    }
    linefft<1>(y, l);
    int o5 = 5*br5(l);
    #pragma unroll
    for (int k=0;k<5;k++) ldsC[fl + o5 + k] = y[k];
    #pragma unroll
    for (int t=0;t<6;t++){
        int j = l + 32*t;
        if (j < 162){
            int k = (j < 81) ? j : j - 81;
            float2 Sk = ldsC[fl + k];
            float2 Sm = ldsC[fl + ((160 - k) % 160)];
            float2 o = (j >= 81)
                ? make_float2(0.5f*(Sk.y + Sm.y), -0.5f*(Sk.x - Sm.x))    // B
                : make_float2(0.5f*(Sk.x + Sm.x),  0.5f*(Sk.y - Sm.y));   // A
            out[baseC + j] = f2h(o);
        }
    }
}

// fused: inverse-z (unscaled) -> *(m2w_r/160) -> forward-z
template<bool PRE>
__global__ __launch_bounds__(256) void fft_z_mid3(RPc P, const float* __restrict__ mask,
                                                 const float* __restrict__ wfull)
{
    __shared__ float2 ldsC[8*162];
    int r = blockIdx.y;
    __half2* C = P.C[r];
    int tid = threadIdx.x, l = tid & 31, g = tid >> 5;
    int fl = g*162;
    size_t baseC   = (size_t)blockIdx.x * 1296 + (size_t)g*162;
    size_t base160 = (size_t)blockIdx.x * 2560 + (size_t)(2*g)*160;
    int o5 = 5*br5(l);
    float ma[5], mb[5];
    if (PRE){
        const __half* M = P.M[r];
        #pragma unroll
        for (int k=0;k<5;k++){
            ma[k] = __half2float(M[base160 + o5 + k]) * SC160;
            mb[k] = __half2float(M[base160 + 160 + o5 + k]) * SC160;
        }
    } else {
        #pragma unroll
        for (int k=0;k<5;k++){
            size_t ia = base160 + o5 + k, ib = base160 + 160 + o5 + k;
            float m1 = mask[ia], m2 = mask[ib];
            ma[k] = m1*m1*wfull[ia*3 + r] * SC160;
            mb[k] = m2*m2*wfull[ib*3 + r] * SC160;
        }
    }
    #pragma unroll
    for (int t=0;t<6;t++){
        int j = l + 32*t;
        if (j < 162) ldsC[fl + j] = h2f(C[baseC + j]);
    }
    float2 y[5];
    #pragma unroll
    for (int n1=0;n1<5;n1++){
        int e = n1*32 + l;
        float2 X;
        if (e <= 80){
            float2 A = ldsC[fl + e], B = ldsC[fl + 81 + e];
            X = make_float2(A.x - B.y, A.y + B.x);
        } else {
            int m = 160 - e;
            float2 A = ldsC[fl + m], B = ldsC[fl + 81 + m];
            X = make_float2(A.x + B.y, B.x - A.y);
        }
        y[n1] = X;
    }
    linefft<-1>(y, l);
    #pragma unroll
    for (int k=0;k<5;k++){
        float a = y[k].x * ma[k];
        float b = y[k].y * mb[k];
        ldsC[fl + o5 + k] = make_float2(a, b);
    }
    #pragma unroll
    for (int n1=0;n1<5;n1++) y[n1] = ldsC[fl + n1*32 + l];
    linefft<1>(y, l);
    #pragma unroll
    for (int k=0;k<5;k++) ldsC[fl + o5 + k] = y[k];
    #pragma unroll
    for (int t=0;t<6;t++){
        int j = l + 32*t;
        if (j < 162){
            int k = (j < 81) ? j : j - 81;
            float2 Sk = ldsC[fl + k];
            float2 Sm = ldsC[fl + ((160 - k) % 160)];
            float2 o = (j >= 81)
                ? make_float2(0.5f*(Sk.y + Sm.y), -0.5f*(Sk.x - Sm.x))
                : make_float2(0.5f*(Sk.x + Sm.x),  0.5f*(Sk.y - Sm.y));
            C[baseC + j] = f2h(o);
        }
    }
}

// final inverse-z (unscaled) + epilogue.
// FIN=0: Ap=v, S[1]+=<z,v>. FIN=1: r=b-v -> rr,pp, S[0]+=<r,r>.
template<int FIN>
__global__ __launch_bounds__(256) void fft_z_fin(const __half2* __restrict__ in,
    const float* __restrict__ zsp, float* __restrict__ Ap,
    const float* __restrict__ bb, float* __restrict__ rrv, float* __restrict__ ppv,
    double* __restrict__ S)
{
    __shared__ float2 ldsC[8*162];
    float* ldsF = (float*)ldsC;      // region g: floats [324g, 324g+320)
    int tid = threadIdx.x, l = tid & 31, g = tid >> 5;
    int fl = g*162;
    size_t baseC   = (size_t)blockIdx.x * 1296 + (size_t)g*162;
    size_t base160 = (size_t)blockIdx.x * 2560 + (size_t)(2*g)*160;
    int o5 = 5*br5(l);
    float za[5], zb[5], pa[5], pb[5];
    #pragma unroll
    for (int k=0;k<5;k++){
        za[k] = zsp[base160 + o5 + k];
        zb[k] = zsp[base160 + 160 + o5 + k];
        if (FIN){
            pa[k] = bb[base160 + o5 + k];
            pb[k] = bb[base160 + 160 + o5 + k];
        }
    }
    #pragma unroll
    for (int t=0;t<6;t++){
        int j = l + 32*t;
        if (j < 162) ldsC[fl + j] = h2f(in[baseC + j]);
    }
    float2 y[5];
    #pragma unroll
    for (int n1=0;n1<5;n1++){
        int e = n1*32 + l;
        float2 X;
        if (e <= 80){
            float2 A = ldsC[fl + e], B = ldsC[fl + 81 + e];
            X = make_float2(A.x - B.y, A.y + B.x);
        } else {
            int m = 160 - e;
            float2 A = ldsC[fl + m], B = ldsC[fl + 81 + m];
            X = make_float2(A.x + B.y, B.x - A.y);
        }
        y[n1] = X;
    }
    linefft<-1>(y, l);
    double acc = 0.0;
    int fb = g*324;
    #pragma unroll
    for (int k=0;k<5;k++){
        float va = LAM_F*za[k] + y[k].x;      // inverse unscaled
        float vb = LAM_F*zb[k] + y[k].y;
        if (FIN == 0){
            acc += (double)za[k]*(double)va + (double)zb[k]*(double)vb;
            ldsF[fb + o5 + k] = va;
            ldsF[fb + 160 + o5 + k] = vb;
        } else {
            float ra = pa[k] - va, rb = pb[k] - vb;
            acc += (double)ra*(double)ra + (double)rb*(double)rb;
            ldsF[fb + o5 + k] = ra;
            ldsF[fb + 160 + o5 + k] = rb;
        }
    }
    #pragma unroll
    for (int t=0;t<10;t++){
        int n = l + 32*t;
        float v = ldsF[fb + n];
        if (FIN == 0){
            Ap[base160 + n] = v;
        } else {
            rrv[base160 + n] = v;
            ppv[base160 + n] = v;
        }
    }
    block_atomic_add(acc, FIN ? &S[0] : &S[1]);
}

// ---------------- y-axis sweeps (strided, guarded half-spectrum, W=8) ----------------
// SGN>0 (fwd): scale 1/160 ; SGN<0 (inv): unscaled.
template<int SGN>
__device__ __forceinline__ void ycompute(float2 (*tile)[WZ+1], int tid){
    int l = tid & 31, q = tid >> 5;
    const float SC = (SGN>0) ? SC160 : 1.f;
    float2 y[5];
    #pragma unroll
    for (int n1=0;n1<5;n1++) y[n1] = tile[l + 32*n1][q];
    linefft<SGN>(y, l);
    int o5 = 5*br5(l);
    #pragma unroll
    for (int k=0;k<5;k++) tile[o5+k][q] = cscale(y[k], SC);
}

// b = zchunk*160 + ix  (zb-outer so line-sharing blocks b, b+160 share an XCD)
template<int SGN>
__global__ __launch_bounds__(256) void fft_y1(__half2* __restrict__ data)
{
    __shared__ float2 tile[NN][WZ+1];
    int b = blockIdx.x;
    int ix = b % 160, zb = (b / 160) * WZ;
    size_t tbase = (size_t)ix*XS + zb;
    int tid = threadIdx.x;
    for (int i = tid; i < NN*WZ; i += 256){
        int row = i >> 3, zi = i & 7;
        tile[row][zi] = (zb + zi < KP) ? h2f(data[tbase + (size_t)row*KP + zi]) : make_float2(0.f,0.f);
    }
    __syncthreads();
    ycompute<SGN>(tile, tid);
    __syncthreads();
    for (int i = tid; i < NN*WZ; i += 256){
        int row = i >> 3, zi = i & 7;
        if (zb + zi < KP) data[tbase + (size_t)row*KP + zi] = f2h(tile[row][zi]);
    }
}

template<int SGN>
__global__ __launch_bounds__(256) void fft_y3(RPc P)
{
    __shared__ float2 tile[NN][WZ+1];
    __half2* data = P.C[blockIdx.y];
    int b = blockIdx.x;
    int ix = b % 160, zb = (b / 160) * WZ;
    size_t tbase = (size_t)ix*XS + zb;
    int tid = threadIdx.x;
    for (int i = tid; i < NN*WZ; i += 256){
        int row = i >> 3, zi = i & 7;
        tile[row][zi] = (zb + zi < KP) ? h2f(data[tbase + (size_t)row*KP + zi]) : make_float2(0.f,0.f);
    }
    __syncthreads();
    ycompute<SGN>(tile, tid);
    __syncthreads();
    for (int i = tid; i < NN*WZ; i += 256){
        int row = i >> 3, zi = i & 7;
        if (zb + zi < KP) data[tbase + (size_t)row*KP + zi] = f2h(tile[row][zi]);
    }
}

// ---------------- x-axis kernels with analytic K ----------------
// spread: one block per (iy, zb). Own-column loads (L2 sector-merged),
// shared fwd-x FFT once, THREE half2 tiles filled with ZERO intervening
// barriers, then ONE barrier + three back-to-back coop stores (MLP burst).
__global__ __launch_bounds__(256) void fft_xK(RPc P, const __half2* __restrict__ in)
{
    __shared__ __half2 t0[NN][9], t1[NN][9], t2[NN][9];
    int b = blockIdx.x;
    int iy = b % 160, zb = (b / 160) * WZ;
    size_t tbase = (size_t)iy*KP + zb;
    int tid = threadIdx.x, l = tid & 31, q = tid >> 5;
    bool okc = (zb + q < KP);
    // own-column loads: no barrier, each group independent
    float2 spec[5];
    #pragma unroll
    for (int n1=0;n1<5;n1++){
        int row = n1*32 + l;
        spec[n1] = okc ? h2f(in[tbase + (size_t)row*XS + q]) : make_float2(0.f,0.f);
    }
    float fy = (float)((iy < 80) ? iy : iy - 160) * (1.f/160.f);
    float fy2 = fy*fy;
    float cy1 = fcos_rev(fy);
    float cy2 = 2.f*cy1*cy1 - 1.f;
    float cy3 = 2.f*cy1*cy2 - cy1;
    QCol qc = make_qcol(1.f, 2.f*cy1, 2.f*cy2, 2.f*cy3, zb + q);
    int o5 = 5*br5(l);
    linefft<1>(spec, l);
    float K3[5][3];
    #pragma unroll
    for (int k=0;k<5;k++) kval3(qc, fy2, o5+k, K3[k]);
    {
        float2 a[5];
        #pragma unroll
        for (int k=0;k<5;k++) a[k] = cscale(spec[k], K3[k][0] * SC160);
        ilinefft_perm(a, l);
        #pragma unroll
        for (int n1=0;n1<5;n1++) t0[n1*32 + l][q] = f2h(a[n1]);
    }
    {
        float2 a[5];
        #pragma unroll
        for (int k=0;k<5;k++) a[k] = cscale(spec[k], K3[k][1] * SC160);
        ilinefft_perm(a, l);
        #pragma unroll
        for (int n1=0;n1<5;n1++) t1[n1*32 + l][q] = f2h(a[n1]);
    }
    {
        float2 a[5];
        #pragma unroll
        for (int k=0;k<5;k++) a[k] = cscale(spec[k], K3[k][2] * SC160);
        ilinefft_perm(a, l);
        #pragma unroll
        for (int n1=0;n1<5;n1++) t2[n1*32 + l][q] = f2h(a[n1]);
    }
    __syncthreads();
    {
        __half2* Cr = P.C[0];
        for (int i = tid; i < NN*WZ; i += 256){
            int row = i >> 3, zi = i & 7;
            if (zb + zi < KP) Cr[tbase + (size_t)row*XS + zi] = t0[row][zi];
        }
    }
    {
        __half2* Cr = P.C[1];
        for (int i = tid; i < NN*WZ; i += 256){
            int row = i >> 3, zi = i & 7;
            if (zb + zi < KP) Cr[tbase + (size_t)row*XS + zi] = t1[row][zi];
        }
    }
    {
        __half2* Cr = P.C[2];
        for (int i = tid; i < NN*WZ; i += 256){
            int row = i >> 3, zi = i & 7;
            if (zb + zi < KP) Cr[tbase + (size_t)row*XS + zi] = t2[row][zi];
        }
    }
}

// gather: CF = invx( sum_r (K_r/160) * fwdx(C_r) ).
// ALL 15 loads hoisted before any FFT (T14 issue-early); one barrier before
// the final coalesced store-transpose.
__global__ __launch_bounds__(256) void fft_xgather(RPc P, __half2* __restrict__ out)
{
    __shared__ __half2 tile[NN][9];
    int b = blockIdx.x;
    int iy = b % 160, zb = (b / 160) * WZ;
    size_t tbase = (size_t)iy*KP + zb;
    int tid = threadIdx.x, l = tid & 31, q = tid >> 5;
    bool okc = (zb + q < KP);
    // hoisted own-column loads for all three buffers
    float2 v0[5], v1[5], v2[5];
    #pragma unroll
    for (int n1=0;n1<5;n1++){
        size_t a = tbase + (size_t)(n1*32 + l)*XS + q;
        v0[n1] = okc ? h2f(P.C[0][a]) : make_float2(0.f,0.f);
        v1[n1] = okc ? h2f(P.C[1][a]) : make_float2(0.f,0.f);
        v2[n1] = okc ? h2f(P.C[2][a]) : make_float2(0.f,0.f);
    }
    float fy = (float)((iy < 80) ? iy : iy - 160) * (1.f/160.f);
    float fy2 = fy*fy;
    float cy1 = fcos_rev(fy);
    float cy2 = 2.f*cy1*cy1 - 1.f;
    float cy3 = 2.f*cy1*cy2 - cy1;
    QCol qc = make_qcol(1.f, 2.f*cy1, 2.f*cy2, 2.f*cy3, zb + q);
    int o5 = 5*br5(l);
    float K3[5][3];
    #pragma unroll
    for (int k=0;k<5;k++) kval3(qc, fy2, o5+k, K3[k]);
    float2 acc[5];
    linefft<1>(v0, l);
    #pragma unroll
    for (int k=0;k<5;k++) acc[k] = cscale(v0[k], K3[k][0] * SC160);
    linefft<1>(v1, l);
    #pragma unroll
    for (int k=0;k<5;k++) acc[k] = cadd(acc[k], cscale(v1[k], K3[k][1] * SC160));
    linefft<1>(v2, l);
    #pragma unroll
    for (int k=0;k<5;k++) acc[k] = cadd(acc[k], cscale(v2[k], K3[k][2] * SC160));
    ilinefft_perm(acc, l);
    #pragma unroll
    for (int n1=0;n1<5;n1++) tile[n1*32 + l][q] = f2h(acc[n1]);
    __syncthreads();
    for (int i = tid; i < NN*WZ; i += 256){
        int row = i >> 3, zi = i & 7;
        if (zb + zi < KP) out[tbase + (size_t)row*XS + zi] = tile[row][zi];
    }
}

// ---------------- setup / CG vector ops ----------------
__global__ __launch_bounds__(256) void m2w_kernel(const float* __restrict__ mask,
        const float* __restrict__ w, __half* __restrict__ M0,
        __half* __restrict__ M1, __half* __restrict__ M2)
{
    int i = blockIdx.x*256 + threadIdx.x;
    float m = mask[i]; float mm = m*m;
    M0[i] = __float2half(mm * w[3*(size_t)i+0]);
    M1[i] = __float2half(mm * w[3*(size_t)i+1]);
    M2[i] = __float2half(mm * w[3*(size_t)i+2]);
}

__global__ __launch_bounds__(256) void copy_kernel(const float* __restrict__ a, float* __restrict__ b){
    int i = blockIdx.x*256 + threadIdx.x;
    b[i] = a[i];
}

#define GSTRIDE (2048*256)
__global__ __launch_bounds__(256) void upd1_kernel(float* __restrict__ x, float* __restrict__ r,
        const float* __restrict__ p, const float* __restrict__ Ap, double* s)
{
    float alpha = (float)(s[0] / (s[1] + 1e-12));
    double acc = 0.0;
    for (int i = blockIdx.x*256 + threadIdx.x; i < N3; i += GSTRIDE){
        x[i] += alpha * p[i];
        float rn = r[i] - alpha * Ap[i];
        r[i] = rn;
        acc += (double)rn * (double)rn;
    }
    block_atomic_add(acc, &s[2]);
}
__global__ void advance_kernel(double* s){
    if (threadIdx.x == 0){
        s[3] = s[2] / (s[0] + 1e-12);   // beta
        s[0] = s[2]; s[1] = 0.0; s[2] = 0.0;
    }
}
__global__ void zero_kernel(double* s){
    if (threadIdx.x < 4) s[threadIdx.x] = 0.0;
}

// ---------------- host orchestration ----------------
extern "C" void kernel_launch(void* const* d_in, const int* in_sizes, int n_in,
                              void* d_out, int out_size, void* d_ws, size_t ws_size,
                              hipStream_t stream)
{
    (void)in_sizes; (void)n_in; (void)out_size;
    const float* w    = (const float*)d_in[0];   // [N3*3], R fastest
    const float* x2   = (const float*)d_in[1];   // [N3]
    const float* mask = (const float*)d_in[2];   // [N3]
    const float* bb   = (const float*)d_in[3];   // [N3]
    float* x = (float*)d_out;
    char* ws = (char*)d_ws;

    size_t off = 0;
    auto alloc = [&](size_t bytes)->void*{
        void* pp = ws + off;
        off += (bytes + 255) & ~(size_t)255;
        return pp;
    };
    const size_t CB = (size_t)NLINES * KP * sizeof(__half2);   // 8.3 MB
    __half2* CF = (__half2*)alloc(CB);
    __half2* C0 = (__half2*)alloc(CB);
    __half2* C1 = (__half2*)alloc(CB);
    __half2* C2 = (__half2*)alloc(CB);
    float*  rr = (float*) alloc((size_t)N3*4);
    float*  pp = (float*) alloc((size_t)N3*4);
    float*  Ap = (float*) alloc((size_t)N3*4);
    double* S  = (double*)alloc(64);
    bool PRE = (ws_size >= off + 3*(((size_t)N3*2 + 255) & ~(size_t)255));
    __half *M0=nullptr, *M1=nullptr, *M2=nullptr;
    if (PRE){
        M0 = (__half*)alloc((size_t)N3*2);
        M1 = (__half*)alloc((size_t)N3*2);
        M2 = (__half*)alloc((size_t)N3*2);
    }
    RPc P;
    P.C[0]=C0; P.C[1]=C1; P.C[2]=C2;
    P.M[0]=M0; P.M[1]=M1; P.M[2]=M2;

    zero_kernel<<<1, 64, 0, stream>>>(S);
    if (PRE) m2w_kernel<<<16000, 256, 0, stream>>>(mask, w, M0, M1, M2);
    copy_kernel<<<16000, 256, 0, stream>>>(x2, x);

    const int GY = NBZ * 160;    // 1760
    // PM: 0 = plain fft of z; 1 = fused p-update. FIN: 1 = initial residual, 0 = CG iter.
    auto applyM = [&](const float* z, int FIN, int PM){
        if (PM) fft_z_first<1><<<1600, 256, 0, stream>>>(z, rr, pp, CF, S);
        else    fft_z_first<0><<<1600, 256, 0, stream>>>(z, rr, pp, CF, S);
        fft_y1<1><<<GY, 256, 0, stream>>>(CF);
        fft_xK<<<GY, 256, 0, stream>>>(P, CF);
        fft_y3<-1><<<dim3(GY,3), 256, 0, stream>>>(P);
        if (PRE) fft_z_mid3<true ><<<dim3(1600,3), 256, 0, stream>>>(P, mask, w);
        else     fft_z_mid3<false><<<dim3(1600,3), 256, 0, stream>>>(P, mask, w);
        fft_y3<1><<<dim3(GY,3), 256, 0, stream>>>(P);
        fft_xgather<<<GY, 256, 0, stream>>>(P, CF);
        fft_y1<-1><<<GY, 256, 0, stream>>>(CF);
        if (FIN) fft_z_fin<1><<<1600, 256, 0, stream>>>(CF, x, Ap, bb, rr, pp, S);
        else     fft_z_fin<0><<<1600, 256, 0, stream>>>(CF, pp, Ap, bb, rr, pp, S);
    };

    // r = b - M(x2); p = r; rs = <r,r>
    applyM(x, 1, 0);

    for (int it = 0; it < 10; it++){
        applyM(pp, 0, (it == 0) ? 0 : 1);          // Ap = M(p), S[1] = <p,Ap>
        upd1_kernel<<<2048, 256, 0, stream>>>(x, rr, pp, Ap, S);
        if (it < 9) advance_kernel<<<1, 64, 0, stream>>>(S);
    }
}